// Round 2
// baseline (6775.481 us; speedup 1.0000x reference)
//
#include <hip/hip_runtime.h>

#define NU 100000
#define NI 50000
#define DD 128
#define HH 128
#define NE 1000000
#define NB 4096

__device__ __forceinline__ float lk(float x) { return fmaxf(0.5f * x, x); }

// ---------- spmm: y[rows[e]] += vals[e] * x[cols[e]], one wave per edge ----------
__global__ __launch_bounds__(256) void spmm_kernel(
    const int* __restrict__ rows, const int* __restrict__ cols,
    const float* __restrict__ vals, const float* __restrict__ x,
    float* __restrict__ y) {
  int gid = blockIdx.x * 256 + threadIdx.x;
  int e = gid >> 6, lane = gid & 63;
  if (e >= NE) return;
  int r = rows[e], c = cols[e];
  float v = vals[e];
  float2 xv = *(const float2*)(x + (size_t)c * DD + 2 * lane);
  float* yp = y + (size_t)r * DD + 2 * lane;
  atomicAdd(yp, v * xv.x);
  atomicAdd(yp + 1, v * xv.y);
}

// ---------- A = E^T @ X  ([128,128], K = N), partial outer products + atomics ----------
__global__ __launch_bounds__(256) void atb_kernel(
    const float* __restrict__ E, const float* __restrict__ X,
    float* __restrict__ A, int N) {
  __shared__ __align__(16) float Es[8][128];
  __shared__ __align__(16) float Xs[8][128];
  float acc[8][8] = {};
  int t = threadIdx.x;
  int ig = (t >> 4) << 3, jg = (t & 15) << 3;
  int rpb = (N + gridDim.x - 1) / gridDim.x;
  int n0 = blockIdx.x * rpb;
  int n1 = min(n0 + rpb, N);
  for (int n = n0; n < n1; n += 8) {
    int nr = min(8, n1 - n);
    __syncthreads();
    for (int k = t; k < nr * 128; k += 256) {
      Es[k >> 7][k & 127] = E[(size_t)(n + (k >> 7)) * DD + (k & 127)];
      Xs[k >> 7][k & 127] = X[(size_t)(n + (k >> 7)) * DD + (k & 127)];
    }
    __syncthreads();
    for (int rr = 0; rr < nr; rr++) {
      float ev[8], xv[8];
#pragma unroll
      for (int a = 0; a < 8; a++) ev[a] = Es[rr][ig + a];
#pragma unroll
      for (int b = 0; b < 8; b++) xv[b] = Xs[rr][jg + b];
#pragma unroll
      for (int a = 0; a < 8; a++)
#pragma unroll
        for (int b = 0; b < 8; b++) acc[a][b] += ev[a] * xv[b];
    }
  }
#pragma unroll
  for (int a = 0; a < 8; a++)
#pragma unroll
    for (int b = 0; b < 8; b++)
      atomicAdd(&A[(ig + a) * HH + (jg + b)], acc[a][b]);
}

// ---------- small 128x128 chain: both sides, one block each ----------
__global__ __launch_bounds__(1024) void chain_kernel(
    const float* __restrict__ A_u, const float* __restrict__ A_i,
    const float* __restrict__ uhy, const float* __restrict__ ihy,
    const float* __restrict__ Wu_l, const float* __restrict__ Wi_l,
    float* __restrict__ B_u, float* __restrict__ B_i) {
  __shared__ __align__(16) float L0[128][128];
  __shared__ __align__(16) float L1[128][128];
  const float* A = blockIdx.x ? A_i : A_u;
  const float* hy = blockIdx.x ? ihy : uhy;
  const float* W = blockIdx.x ? Wi_l : Wu_l;
  float* Bo = blockIdx.x ? B_i : B_u;
  int t = threadIdx.x, j = t & 127, ib = t >> 7;
  for (int k = t; k < 16384; k += 1024) L0[k >> 7][k & 127] = A[k];
  __syncthreads();
  {  // L1 = leaky(hy^T @ L0)
    float acc[16] = {};
    for (int k = 0; k < 128; k++) {
      float lv = L0[k][j];
#pragma unroll
      for (int r = 0; r < 16; r++) acc[r] += hy[k * HH + (ib << 4) + r] * lv;
    }
    for (int r = 0; r < 16; r++) L1[(ib << 4) + r][j] = lk(acc[r]);
  }
  __syncthreads();
  float (*in)[128] = L1;
  float (*out)[128] = L0;
  for (int s = 0; s < 3; s++) {  // lat = leaky(Wk^T @ lat) + lat
    const float* Wk = W + s * HH * HH;
    float acc[16] = {};
    for (int k = 0; k < 128; k++) {
      float lv = in[k][j];
#pragma unroll
      for (int r = 0; r < 16; r++) acc[r] += Wk[k * HH + (ib << 4) + r] * lv;
    }
    for (int r = 0; r < 16; r++) {
      int i = (ib << 4) + r;
      out[i][j] = lk(acc[r]) + in[i][j];
    }
    __syncthreads();
    float (*tmp)[128] = in; in = out; out = tmp;
  }
  {  // B = hy @ lat
    float acc[16] = {};
    for (int k = 0; k < 128; k++) {
      float lv = in[k][j];
#pragma unroll
      for (int r = 0; r < 16; r++) acc[r] += hy[((ib << 4) + r) * HH + k] * lv;
    }
    for (int r = 0; r < 16; r++) Bo[((ib << 4) + r) * HH + j] = acc[r];
  }
}

// ---------- fused: h=leaky(E@B); cur += leaky(gnn)+h; sum += cur ----------
__global__ __launch_bounds__(256) void nmul_upd_kernel(
    const float* __restrict__ E, const float* __restrict__ Bm,
    const float* __restrict__ gnn, float* __restrict__ cur,
    float* __restrict__ sum, int N) {
  __shared__ __align__(16) float Bs[128][132];
  __shared__ __align__(16) float Es[128][132];
  int t = threadIdx.x;
  int rg = t >> 4, dg = t & 15;
  for (int k = t; k < 16384; k += 256) Bs[k >> 7][k & 127] = Bm[k];
  int ntiles = (N + 127) >> 7;
  for (int tile = blockIdx.x; tile < ntiles; tile += gridDim.x) {
    int n0 = tile << 7;
    int nr = min(128, N - n0);
    __syncthreads();
    for (int k = t; k < 16384; k += 256) {
      int rr = k >> 7, cc = k & 127;
      Es[rr][cc] = (rr < nr) ? E[(size_t)(n0 + rr) * DD + cc] : 0.f;
    }
    __syncthreads();
    float acc[8][8] = {};
    for (int h4 = 0; h4 < 128; h4 += 4) {
      float4 ev[8];
#pragma unroll
      for (int a = 0; a < 8; a++) ev[a] = *(const float4*)&Es[rg + (a << 4)][h4];
#pragma unroll
      for (int hh = 0; hh < 4; hh++) {
        float4 b0 = *(const float4*)&Bs[h4 + hh][dg << 2];
        float4 b1 = *(const float4*)&Bs[h4 + hh][(dg << 2) + 64];
#pragma unroll
        for (int a = 0; a < 8; a++) {
          float e = ((const float*)&ev[a])[hh];
          acc[a][0] += e * b0.x; acc[a][1] += e * b0.y;
          acc[a][2] += e * b0.z; acc[a][3] += e * b0.w;
          acc[a][4] += e * b1.x; acc[a][5] += e * b1.y;
          acc[a][6] += e * b1.z; acc[a][7] += e * b1.w;
        }
      }
    }
#pragma unroll
    for (int a = 0; a < 8; a++) {
      int n = n0 + rg + (a << 4);
      if (n < N) {
        size_t base = (size_t)n * DD + (dg << 2);
        float4 g0 = *(const float4*)(gnn + base);
        float4 g1 = *(const float4*)(gnn + base + 64);
        float4 c0 = *(const float4*)(cur + base);
        float4 c1 = *(const float4*)(cur + base + 64);
        float4 s0 = *(const float4*)(sum + base);
        float4 s1 = *(const float4*)(sum + base + 64);
        c0.x += lk(g0.x) + lk(acc[a][0]); c0.y += lk(g0.y) + lk(acc[a][1]);
        c0.z += lk(g0.z) + lk(acc[a][2]); c0.w += lk(g0.w) + lk(acc[a][3]);
        c1.x += lk(g1.x) + lk(acc[a][4]); c1.y += lk(g1.y) + lk(acc[a][5]);
        c1.z += lk(g1.z) + lk(acc[a][6]); c1.w += lk(g1.w) + lk(acc[a][7]);
        s0.x += c0.x; s0.y += c0.y; s0.z += c0.z; s0.w += c0.w;
        s1.x += c1.x; s1.y += c1.y; s1.z += c1.z; s1.w += c1.w;
        *(float4*)(cur + base) = c0; *(float4*)(cur + base + 64) = c1;
        *(float4*)(sum + base) = s0; *(float4*)(sum + base + 64) = s1;
      }
    }
  }
}

// ---------- ssl gather: og=leaky(gnn[id]); oh=leaky(E[id]@B) ----------
__global__ __launch_bounds__(128) void sslgath_kernel(
    const int* __restrict__ ids, const float* __restrict__ gnn,
    const float* __restrict__ E, const float* __restrict__ Bm,
    float* __restrict__ og, float* __restrict__ oh) {
  int b = blockIdx.x, d = threadIdx.x;
  int id = ids[b];
  __shared__ float Es[128];
  Es[d] = E[(size_t)id * DD + d];
  og[(size_t)b * DD + d] = lk(gnn[(size_t)id * DD + d]);
  __syncthreads();
  float acc = 0.f;
  for (int k = 0; k < 128; k++) acc += Es[k] * Bm[k * DD + d];
  oh[(size_t)b * DD + d] = lk(acc);
}

// ---------- preds ----------
__global__ __launch_bounds__(256) void preds_kernel(
    const int* __restrict__ uids, const int* __restrict__ iids,
    const float* __restrict__ su, const float* __restrict__ si,
    float* __restrict__ outp) {
  int gid = blockIdx.x * 256 + threadIdx.x;
  int w = gid >> 6, lane = gid & 63;
  if (w >= NB) return;
  int u = uids[w], it = iids[w];
  float2 a = *(const float2*)(su + (size_t)u * DD + 2 * lane);
  float2 b = *(const float2*)(si + (size_t)it * DD + 2 * lane);
  float d = a.x * b.x + a.y * b.y;
#pragma unroll
  for (int o = 32; o > 0; o >>= 1) d += __shfl_down(d, o);
  if (lane == 0) outp[w] = d;
}

// ---------- sum of squares (reg) ----------
__global__ __launch_bounds__(256) void sumsq_kernel(
    const float* __restrict__ x, int n, float* __restrict__ outp) {
  float acc = 0.f;
  for (int i = blockIdx.x * 256 + threadIdx.x; i < n; i += gridDim.x * 256) {
    float v = x[i];
    acc += v * v;
  }
#pragma unroll
  for (int o = 32; o > 0; o >>= 1) acc += __shfl_down(acc, o);
  __shared__ float s[4];
  if ((threadIdx.x & 63) == 0) s[threadIdx.x >> 6] = acc;
  __syncthreads();
  if (threadIdx.x == 0) atomicAdd(outp, s[0] + s[1] + s[2] + s[3]);
}

// ---------- ssl: l2norm rows + hyperLat = hn @ Wt (IN-PLACE on hg/gg) ----------
__global__ __launch_bounds__(128) void xform_kernel(
    float* __restrict__ hyp_g, float* __restrict__ gnn_g,
    const float* __restrict__ Wt_l) {
  int r = blockIdx.x, d = threadIdx.x;
  __shared__ float hn[128];
  __shared__ float red[4];
  float hv = hyp_g[(size_t)r * DD + d];
  float gv = gnn_g[(size_t)r * DD + d];
  float h2 = hv * hv, g2 = gv * gv;
#pragma unroll
  for (int o = 32; o > 0; o >>= 1) { h2 += __shfl_down(h2, o); g2 += __shfl_down(g2, o); }
  if ((d & 63) == 0) { red[(d >> 6) * 2] = h2; red[(d >> 6) * 2 + 1] = g2; }
  __syncthreads();
  float hnorm = sqrtf(red[0] + red[2]);
  float gnorm = sqrtf(red[1] + red[3]);
  float hnv = hv / fmaxf(hnorm, 1e-12f);
  float gnv = gv / fmaxf(gnorm, 1e-12f);
  gnn_g[(size_t)r * DD + d] = gnv;   // gn (in place)
  hn[d] = hnv;
  __syncthreads();
  float acc = 0.f;
  for (int k = 0; k < 128; k++) acc += hn[k] * Wt_l[k * DD + d];
  hyp_g[(size_t)r * DD + d] = acc;   // hw (in place)
}

// ---------- gram: neg[i] += sum_j exp(gn_i . hw_j) ----------
__global__ __launch_bounds__(256) void gram_kernel(
    const float* __restrict__ gn, const float* __restrict__ hw,
    float* __restrict__ neg) {
  __shared__ __align__(16) float Gs[128][132];
  __shared__ __align__(16) float Hs[128][132];
  __shared__ float negs[128];
  int t = threadIdx.x;
  int ig = t >> 4, jg = t & 15;
  int i0 = blockIdx.x << 7, j0 = blockIdx.y << 7;
  for (int k = t; k < 16384; k += 256) {
    int rr = k >> 7, cc = k & 127;
    Gs[rr][cc] = gn[(size_t)(i0 + rr) * DD + cc];
    Hs[rr][cc] = hw[(size_t)(j0 + rr) * DD + cc];
  }
  if (t < 128) negs[t] = 0.f;
  __syncthreads();
  float acc[8][8] = {};
  for (int h4 = 0; h4 < 128; h4 += 4) {
    float4 gv[8], hv[8];
#pragma unroll
    for (int a = 0; a < 8; a++) gv[a] = *(const float4*)&Gs[ig + (a << 4)][h4];
#pragma unroll
    for (int b = 0; b < 8; b++) hv[b] = *(const float4*)&Hs[jg + (b << 4)][h4];
#pragma unroll
    for (int hh = 0; hh < 4; hh++)
#pragma unroll
      for (int a = 0; a < 8; a++) {
        float g = ((const float*)&gv[a])[hh];
#pragma unroll
        for (int b = 0; b < 8; b++) acc[a][b] += g * ((const float*)&hv[b])[hh];
      }
  }
#pragma unroll
  for (int a = 0; a < 8; a++) {
    float s = 0.f;
#pragma unroll
    for (int b = 0; b < 8; b++) s += expf(acc[a][b]);
    atomicAdd(&negs[ig + (a << 4)], s);
  }
  __syncthreads();
  if (t < 128) atomicAdd(&neg[i0 + t], negs[t]);
}

// ---------- ssl finalize ----------
__global__ __launch_bounds__(256) void sslfin_kernel(
    const float* __restrict__ gn, const float* __restrict__ hw,
    const float* __restrict__ neg, float* __restrict__ outp) {
  int gid = blockIdx.x * 256 + threadIdx.x;
  int w = gid >> 6, lane = gid & 63;
  if (w >= NB) return;
  float2 a = *(const float2*)(gn + (size_t)w * DD + 2 * lane);
  float2 b = *(const float2*)(hw + (size_t)w * DD + 2 * lane);
  float d = a.x * b.x + a.y * b.y;
#pragma unroll
  for (int o = 32; o > 0; o >>= 1) d += __shfl_down(d, o);
  if (lane == 0) {
    float pos = expf(d);
    float v = -logf(pos / (neg[w] + 1e-8f) + 1e-8f);
    atomicAdd(outp, v);
  }
}

extern "C" void kernel_launch(void* const* d_in, const int* in_sizes, int n_in,
                              void* d_out, int out_size, void* d_ws, size_t ws_size,
                              hipStream_t stream) {
  (void)in_sizes; (void)n_in; (void)out_size; (void)ws_size;
  const int* uids = (const int*)d_in[0];
  const int* iids = (const int*)d_in[1];
  const int* arow = (const int*)d_in[2];
  const int* acol = (const int*)d_in[3];
  const float* avals = (const float*)d_in[4];
  const float* uE = (const float*)d_in[5];
  const float* iE = (const float*)d_in[6];
  const float* uhy = (const float*)d_in[7];
  const float* ihy = (const float*)d_in[8];
  const float* Wu = (const float*)d_in[9];
  const float* Wi = (const float*)d_in[10];
  const float* Wt = (const float*)d_in[11];
  float* out = (float*)d_out;

  // workspace layout (~236 MB)
  float* p = (float*)d_ws;
  float* cur_u = p; p += (size_t)NU * DD;
  float* sum_u = p; p += (size_t)NU * DD;
  float* gnn_u = p; p += (size_t)NU * DD;
  float* cur_i = p; p += (size_t)NI * DD;
  float* sum_i = p; p += (size_t)NI * DD;
  float* gnn_i = p; p += (size_t)NI * DD;
  float* A_u = p; p += HH * DD;
  float* A_i = p; p += HH * DD;
  float* B_u = p; p += HH * DD;
  float* B_i = p; p += HH * DD;
  float* gg = p; p += (size_t)NB * DD;   // gathered gnn -> gn (in place)
  float* gh = p; p += (size_t)NB * DD;   // gathered hyp -> hw (in place)
  float* negb = p; p += 4 * NB;

  hipMemcpyAsync(cur_u, uE, (size_t)NU * DD * 4, hipMemcpyDeviceToDevice, stream);
  hipMemcpyAsync(sum_u, uE, (size_t)NU * DD * 4, hipMemcpyDeviceToDevice, stream);
  hipMemcpyAsync(cur_i, iE, (size_t)NI * DD * 4, hipMemcpyDeviceToDevice, stream);
  hipMemcpyAsync(sum_i, iE, (size_t)NI * DD * 4, hipMemcpyDeviceToDevice, stream);
  hipMemsetAsync(out + NB, 0, 2 * sizeof(float), stream);
  hipMemsetAsync(negb, 0, 4 * NB * sizeof(float), stream);

  for (int l = 0; l < 2; l++) {
    const float* Wt_l = Wt + (size_t)l * DD * DD;
    hipMemsetAsync(gnn_u, 0, (size_t)NU * DD * 4, stream);
    hipMemsetAsync(gnn_i, 0, (size_t)NI * DD * 4, stream);
    hipMemsetAsync(A_u, 0, 2 * HH * DD * 4, stream);  // A_u + A_i contiguous
    spmm_kernel<<<NE / 4, 256, 0, stream>>>(arow, acol, avals, cur_i, gnn_u);
    spmm_kernel<<<NE / 4, 256, 0, stream>>>(acol, arow, avals, cur_u, gnn_i);
    atb_kernel<<<512, 256, 0, stream>>>(uE, cur_u, A_u, NU);
    atb_kernel<<<512, 256, 0, stream>>>(iE, cur_i, A_i, NI);
    chain_kernel<<<2, 1024, 0, stream>>>(A_u, A_i, uhy, ihy,
        Wu + (size_t)l * 3 * HH * HH, Wi + (size_t)l * 3 * HH * HH, B_u, B_i);

    // ---- user side ----
    sslgath_kernel<<<NB, 128, 0, stream>>>(uids, gnn_u, uE, B_u, gg, gh);
    nmul_upd_kernel<<<512, 256, 0, stream>>>(uE, B_u, gnn_u, cur_u, sum_u, NU);
    xform_kernel<<<NB, 128, 0, stream>>>(gh, gg, Wt_l);
    gram_kernel<<<dim3(NB / 128, NB / 128), 256, 0, stream>>>(gg, gh, negb + (2 * l) * NB);
    sslfin_kernel<<<NB / 4, 256, 0, stream>>>(gg, gh, negb + (2 * l) * NB, out + NB);

    // ---- item side ----
    sslgath_kernel<<<NB, 128, 0, stream>>>(iids, gnn_i, iE, B_i, gg, gh);
    nmul_upd_kernel<<<512, 256, 0, stream>>>(iE, B_i, gnn_i, cur_i, sum_i, NI);
    xform_kernel<<<NB, 128, 0, stream>>>(gh, gg, Wt_l);
    gram_kernel<<<dim3(NB / 128, NB / 128), 256, 0, stream>>>(gg, gh, negb + (2 * l + 1) * NB);
    sslfin_kernel<<<NB / 4, 256, 0, stream>>>(gg, gh, negb + (2 * l + 1) * NB, out + NB);
  }

  preds_kernel<<<NB / 4, 256, 0, stream>>>(uids, iids, sum_u, sum_i, out);
  sumsq_kernel<<<2048, 256, 0, stream>>>(uE, NU * DD, out + NB + 1);
  sumsq_kernel<<<1024, 256, 0, stream>>>(iE, NI * DD, out + NB + 1);
  sumsq_kernel<<<64, 256, 0, stream>>>(uhy, DD * HH, out + NB + 1);
  sumsq_kernel<<<64, 256, 0, stream>>>(ihy, DD * HH, out + NB + 1);
}

// Round 4
// 3602.534 us; speedup vs baseline: 1.8808x; 1.8808x over previous
//
#include <hip/hip_runtime.h>

#define NU 100000
#define NI 50000
#define DD 128
#define HH 128
#define NE 1000000
#define NB 4096
#define SCHUNK 2048

__device__ __forceinline__ float lk(float x) { return fmaxf(0.5f * x, x); }

// ================= CSR build =================
__global__ __launch_bounds__(256) void hist_kernel(const int* __restrict__ idx,
                                                   int* __restrict__ deg, int n) {
  int e = blockIdx.x * 256 + threadIdx.x;
  if (e < n) atomicAdd(&deg[idx[e]], 1);
}

__global__ __launch_bounds__(256) void scan_bsum(const int* __restrict__ deg,
                                                 int* __restrict__ bsum, int N) {
  int b = blockIdx.x, t = threadIdx.x;
  int base = b * SCHUNK;
  int s = 0;
  for (int i = t; i < SCHUNK; i += 256) {
    int g = base + i;
    if (g < N) s += deg[g];
  }
#pragma unroll
  for (int o = 32; o > 0; o >>= 1) s += __shfl_down(s, o);
  __shared__ int ws[4];
  if ((t & 63) == 0) ws[t >> 6] = s;
  __syncthreads();
  if (t == 0) bsum[b] = ws[0] + ws[1] + ws[2] + ws[3];
}

__global__ __launch_bounds__(256) void scan_top(int* __restrict__ bsum, int G) {
  int t = threadIdx.x;
  __shared__ int sh[256];
  int v = (t < G) ? bsum[t] : 0;
  sh[t] = v;
  __syncthreads();
  for (int o = 1; o < 256; o <<= 1) {
    int add = (t >= o) ? sh[t - o] : 0;
    __syncthreads();
    sh[t] += add;
    __syncthreads();
  }
  if (t < G) bsum[t] = sh[t] - v;  // exclusive
}

// deg may alias cursor: each element read+written only by its owning thread.
__global__ __launch_bounds__(256) void scan_write(const int* __restrict__ deg,
                                                  const int* __restrict__ bsumx,
                                                  int* __restrict__ rowptr,
                                                  int* __restrict__ cursor,
                                                  int N, int total) {
  int b = blockIdx.x, t = threadIdx.x;
  int base = b * SCHUNK + t * 8;
  int v[8], s = 0;
#pragma unroll
  for (int i = 0; i < 8; i++) {
    int g = base + i;
    v[i] = (g < N) ? deg[g] : 0;
    s += v[i];
  }
  __shared__ int sh[256];
  sh[t] = s;
  __syncthreads();
  for (int o = 1; o < 256; o <<= 1) {
    int add = (t >= o) ? sh[t - o] : 0;
    __syncthreads();
    sh[t] += add;
    __syncthreads();
  }
  int off = bsumx[b] + sh[t] - s;
#pragma unroll
  for (int i = 0; i < 8; i++) {
    int g = base + i;
    if (g < N) { rowptr[g] = off; cursor[g] = off; }
    off += v[i];
  }
  if (b == 0 && t == 0) rowptr[N] = total;
}

__global__ __launch_bounds__(256) void scatter_kernel(const int* __restrict__ idx,
                                                      int* __restrict__ cursor,
                                                      int* __restrict__ eidx, int n) {
  int e = blockIdx.x * 256 + threadIdx.x;
  if (e < n) {
    int p = atomicAdd(&cursor[idx[e]], 1);
    eidx[p] = e;
  }
}

// ================= spmm via CSR: wave per row, no atomics =================
__global__ __launch_bounds__(256) void spmm_csr_kernel(
    const int* __restrict__ rowptr, const int* __restrict__ eidx,
    const int* __restrict__ gcol, const float* __restrict__ vals,
    const float* __restrict__ x, float* __restrict__ y, int N) {
  int w = (blockIdx.x * 256 + threadIdx.x) >> 6;
  int lane = threadIdx.x & 63;
  if (w >= N) return;
  int j = rowptr[w], j1 = rowptr[w + 1];
  float ax = 0.f, ay = 0.f;
  for (; j + 1 < j1; j += 2) {
    int e0 = eidx[j], e1 = eidx[j + 1];
    int c0 = gcol[e0], c1 = gcol[e1];
    float v0 = vals[e0], v1 = vals[e1];
    float2 x0 = *(const float2*)(x + (size_t)c0 * DD + 2 * lane);
    float2 x1 = *(const float2*)(x + (size_t)c1 * DD + 2 * lane);
    ax += v0 * x0.x + v1 * x1.x;
    ay += v0 * x0.y + v1 * x1.y;
  }
  if (j < j1) {
    int e0 = eidx[j];
    int c0 = gcol[e0];
    float v0 = vals[e0];
    float2 x0 = *(const float2*)(x + (size_t)c0 * DD + 2 * lane);
    ax += v0 * x0.x;
    ay += v0 * x0.y;
  }
  float2 r;
  r.x = ax; r.y = ay;
  *(float2*)(y + (size_t)w * DD + 2 * lane) = r;
}

// ---------- A = E^T @ X  ([128,128], K = N), partial outer products + atomics ----------
__global__ __launch_bounds__(256) void atb_kernel(
    const float* __restrict__ E, const float* __restrict__ X,
    float* __restrict__ A, int N) {
  __shared__ __align__(16) float Es[8][128];
  __shared__ __align__(16) float Xs[8][128];
  float acc[8][8] = {};
  int t = threadIdx.x;
  int ig = (t >> 4) << 3, jg = (t & 15) << 3;
  int rpb = (N + gridDim.x - 1) / gridDim.x;
  int n0 = blockIdx.x * rpb;
  int n1 = min(n0 + rpb, N);
  for (int n = n0; n < n1; n += 8) {
    int nr = min(8, n1 - n);
    __syncthreads();
    for (int k = t; k < nr * 128; k += 256) {
      Es[k >> 7][k & 127] = E[(size_t)(n + (k >> 7)) * DD + (k & 127)];
      Xs[k >> 7][k & 127] = X[(size_t)(n + (k >> 7)) * DD + (k & 127)];
    }
    __syncthreads();
    for (int rr = 0; rr < nr; rr++) {
      float ev[8], xv[8];
#pragma unroll
      for (int a = 0; a < 8; a++) ev[a] = Es[rr][ig + a];
#pragma unroll
      for (int b = 0; b < 8; b++) xv[b] = Xs[rr][jg + b];
#pragma unroll
      for (int a = 0; a < 8; a++)
#pragma unroll
        for (int b = 0; b < 8; b++) acc[a][b] += ev[a] * xv[b];
    }
  }
#pragma unroll
  for (int a = 0; a < 8; a++)
#pragma unroll
    for (int b = 0; b < 8; b++)
      atomicAdd(&A[(ig + a) * HH + (jg + b)], acc[a][b]);
}

// ---------- chain: column-strip parallel, W staged in LDS ----------
// grid = 16 blocks (2 sides x 8 strips of 16 cols), 256 threads
__global__ __launch_bounds__(256) void chain_kernel(
    const float* __restrict__ A_u, const float* __restrict__ A_i,
    const float* __restrict__ uhy, const float* __restrict__ ihy,
    const float* __restrict__ Wu_l, const float* __restrict__ Wi_l,
    float* __restrict__ B_u, float* __restrict__ B_i) {
  __shared__ float Wb[128 * 132];
  __shared__ float LA[128][16];
  __shared__ float LB[128][16];
  int side = blockIdx.x >> 3, strip = blockIdx.x & 7;
  const float* A = side ? A_i : A_u;
  const float* hy = side ? ihy : uhy;
  const float* W = side ? Wi_l : Wu_l;
  float* Bo = side ? B_i : B_u;
  int t = threadIdx.x;
  int j0 = strip * 16;
  for (int i = t; i < 2048; i += 256) LA[i >> 4][i & 15] = A[(i >> 4) * 128 + j0 + (i & 15)];
  for (int i = t; i < 16384; i += 256) Wb[(i >> 7) * 132 + (i & 127)] = hy[i];
  __syncthreads();
  int jc = t & 15, i0 = (t >> 4) * 8;
  {  // LB = leaky(hy^T @ A_strip)
    float acc[8] = {};
    for (int k = 0; k < 128; k++) {
      float lv = LA[k][jc];
      const float* wr = &Wb[k * 132 + i0];
#pragma unroll
      for (int a = 0; a < 8; a++) acc[a] += wr[a] * lv;
    }
#pragma unroll
    for (int a = 0; a < 8; a++) LB[i0 + a][jc] = lk(acc[a]);
  }
  __syncthreads();
  float (*pin)[16] = LB;
  float (*pout)[16] = LA;
  for (int s = 0; s < 3; s++) {  // lat = leaky(Ws^T @ lat) + lat
    for (int i = t; i < 16384; i += 256) Wb[(i >> 7) * 132 + (i & 127)] = W[s * 16384 + i];
    __syncthreads();
    float acc[8] = {};
    for (int k = 0; k < 128; k++) {
      float lv = pin[k][jc];
      const float* wr = &Wb[k * 132 + i0];
#pragma unroll
      for (int a = 0; a < 8; a++) acc[a] += wr[a] * lv;
    }
#pragma unroll
    for (int a = 0; a < 8; a++) pout[i0 + a][jc] = lk(acc[a]) + pin[i0 + a][jc];
    __syncthreads();
    float (*tmp)[16] = pin; pin = pout; pout = tmp;
  }
  // B_strip = hy @ lat
  for (int i = t; i < 16384; i += 256) Wb[(i >> 7) * 132 + (i & 127)] = hy[i];
  __syncthreads();
  {
    int i = t >> 1, jb = (t & 1) * 8;
    float acc[8] = {};
    for (int k = 0; k < 128; k++) {
      float hv = Wb[i * 132 + k];
      const float* lr = &pin[k][jb];
#pragma unroll
      for (int b = 0; b < 8; b++) acc[b] += hv * lr[b];
    }
#pragma unroll
    for (int b = 0; b < 8; b++) Bo[i * 128 + j0 + jb + b] = acc[b];
  }
}

// ---------- fused: h=leaky(E@B); cur += leaky(gnn)+h; sum += cur ----------
__global__ __launch_bounds__(256) void nmul_upd_kernel(
    const float* __restrict__ E, const float* __restrict__ Bm,
    const float* __restrict__ gnn, float* __restrict__ cur,
    float* __restrict__ sum, int N) {
  __shared__ __align__(16) float Bs[128][132];
  __shared__ __align__(16) float Es[128][132];
  int t = threadIdx.x;
  int rg = t >> 4, dg = t & 15;
  for (int k = t; k < 16384; k += 256) Bs[k >> 7][k & 127] = Bm[k];
  int ntiles = (N + 127) >> 7;
  for (int tile = blockIdx.x; tile < ntiles; tile += gridDim.x) {
    int n0 = tile << 7;
    int nr = min(128, N - n0);
    __syncthreads();
    for (int k = t; k < 16384; k += 256) {
      int rr = k >> 7, cc = k & 127;
      Es[rr][cc] = (rr < nr) ? E[(size_t)(n0 + rr) * DD + cc] : 0.f;
    }
    __syncthreads();
    float acc[8][8] = {};
    for (int h4 = 0; h4 < 128; h4 += 4) {
      float4 ev[8];
#pragma unroll
      for (int a = 0; a < 8; a++) ev[a] = *(const float4*)&Es[rg + (a << 4)][h4];
#pragma unroll
      for (int hh = 0; hh < 4; hh++) {
        float4 b0 = *(const float4*)&Bs[h4 + hh][dg << 2];
        float4 b1 = *(const float4*)&Bs[h4 + hh][(dg << 2) + 64];
#pragma unroll
        for (int a = 0; a < 8; a++) {
          float e = ((const float*)&ev[a])[hh];
          acc[a][0] += e * b0.x; acc[a][1] += e * b0.y;
          acc[a][2] += e * b0.z; acc[a][3] += e * b0.w;
          acc[a][4] += e * b1.x; acc[a][5] += e * b1.y;
          acc[a][6] += e * b1.z; acc[a][7] += e * b1.w;
        }
      }
    }
#pragma unroll
    for (int a = 0; a < 8; a++) {
      int n = n0 + rg + (a << 4);
      if (n < N) {
        size_t base = (size_t)n * DD + (dg << 2);
        float4 g0 = *(const float4*)(gnn + base);
        float4 g1 = *(const float4*)(gnn + base + 64);
        float4 c0 = *(const float4*)(cur + base);
        float4 c1 = *(const float4*)(cur + base + 64);
        float4 s0 = *(const float4*)(sum + base);
        float4 s1 = *(const float4*)(sum + base + 64);
        c0.x += lk(g0.x) + lk(acc[a][0]); c0.y += lk(g0.y) + lk(acc[a][1]);
        c0.z += lk(g0.z) + lk(acc[a][2]); c0.w += lk(g0.w) + lk(acc[a][3]);
        c1.x += lk(g1.x) + lk(acc[a][4]); c1.y += lk(g1.y) + lk(acc[a][5]);
        c1.z += lk(g1.z) + lk(acc[a][6]); c1.w += lk(g1.w) + lk(acc[a][7]);
        s0.x += c0.x; s0.y += c0.y; s0.z += c0.z; s0.w += c0.w;
        s1.x += c1.x; s1.y += c1.y; s1.z += c1.z; s1.w += c1.w;
        *(float4*)(cur + base) = c0; *(float4*)(cur + base + 64) = c1;
        *(float4*)(sum + base) = s0; *(float4*)(sum + base + 64) = s1;
      }
    }
  }
}

// ---------- ssl gather: og=leaky(gnn[id]); oh=leaky(E[id]@B) ----------
__global__ __launch_bounds__(128) void sslgath_kernel(
    const int* __restrict__ ids, const float* __restrict__ gnn,
    const float* __restrict__ E, const float* __restrict__ Bm,
    float* __restrict__ og, float* __restrict__ oh) {
  int b = blockIdx.x, d = threadIdx.x;
  int id = ids[b];
  __shared__ float Es[128];
  Es[d] = E[(size_t)id * DD + d];
  og[(size_t)b * DD + d] = lk(gnn[(size_t)id * DD + d]);
  __syncthreads();
  float acc = 0.f;
  for (int k = 0; k < 128; k++) acc += Es[k] * Bm[k * DD + d];
  oh[(size_t)b * DD + d] = lk(acc);
}

// ---------- preds ----------
__global__ __launch_bounds__(256) void preds_kernel(
    const int* __restrict__ uids, const int* __restrict__ iids,
    const float* __restrict__ su, const float* __restrict__ si,
    float* __restrict__ outp) {
  int gid = blockIdx.x * 256 + threadIdx.x;
  int w = gid >> 6, lane = gid & 63;
  if (w >= NB) return;
  int u = uids[w], it = iids[w];
  float2 a = *(const float2*)(su + (size_t)u * DD + 2 * lane);
  float2 b = *(const float2*)(si + (size_t)it * DD + 2 * lane);
  float d = a.x * b.x + a.y * b.y;
#pragma unroll
  for (int o = 32; o > 0; o >>= 1) d += __shfl_down(d, o);
  if (lane == 0) outp[w] = d;
}

// ---------- sum of squares (reg) ----------
__global__ __launch_bounds__(256) void sumsq_kernel(
    const float* __restrict__ x, int n, float* __restrict__ outp) {
  float acc = 0.f;
  for (int i = blockIdx.x * 256 + threadIdx.x; i < n; i += gridDim.x * 256) {
    float v = x[i];
    acc += v * v;
  }
#pragma unroll
  for (int o = 32; o > 0; o >>= 1) acc += __shfl_down(acc, o);
  __shared__ float s[4];
  if ((threadIdx.x & 63) == 0) s[threadIdx.x >> 6] = acc;
  __syncthreads();
  if (threadIdx.x == 0) atomicAdd(outp, s[0] + s[1] + s[2] + s[3]);
}

// ---------- ssl: l2norm rows + hyperLat = hn @ Wt (IN-PLACE on hg/gg) ----------
__global__ __launch_bounds__(128) void xform_kernel(
    float* __restrict__ hyp_g, float* __restrict__ gnn_g,
    const float* __restrict__ Wt_l) {
  int r = blockIdx.x, d = threadIdx.x;
  __shared__ float hn[128];
  __shared__ float red[4];
  float hv = hyp_g[(size_t)r * DD + d];
  float gv = gnn_g[(size_t)r * DD + d];
  float h2 = hv * hv, g2 = gv * gv;
#pragma unroll
  for (int o = 32; o > 0; o >>= 1) { h2 += __shfl_down(h2, o); g2 += __shfl_down(g2, o); }
  if ((d & 63) == 0) { red[(d >> 6) * 2] = h2; red[(d >> 6) * 2 + 1] = g2; }
  __syncthreads();
  float hnorm = sqrtf(red[0] + red[2]);
  float gnorm = sqrtf(red[1] + red[3]);
  float hnv = hv / fmaxf(hnorm, 1e-12f);
  float gnv = gv / fmaxf(gnorm, 1e-12f);
  gnn_g[(size_t)r * DD + d] = gnv;
  hn[d] = hnv;
  __syncthreads();
  float acc = 0.f;
  for (int k = 0; k < 128; k++) acc += hn[k] * Wt_l[k * DD + d];
  hyp_g[(size_t)r * DD + d] = acc;
}

// ---------- gram: neg[i] += sum_j exp(gn_i . hw_j) ----------
__global__ __launch_bounds__(256) void gram_kernel(
    const float* __restrict__ gn, const float* __restrict__ hw,
    float* __restrict__ neg) {
  __shared__ __align__(16) float Gs[128][132];
  __shared__ __align__(16) float Hs[128][132];
  __shared__ float negs[128];
  int t = threadIdx.x;
  int ig = t >> 4, jg = t & 15;
  int i0 = blockIdx.x << 7, j0 = blockIdx.y << 7;
  for (int k = t; k < 16384; k += 256) {
    int rr = k >> 7, cc = k & 127;
    Gs[rr][cc] = gn[(size_t)(i0 + rr) * DD + cc];
    Hs[rr][cc] = hw[(size_t)(j0 + rr) * DD + cc];
  }
  if (t < 128) negs[t] = 0.f;
  __syncthreads();
  float acc[8][8] = {};
  for (int h4 = 0; h4 < 128; h4 += 4) {
    float4 gv[8], hv[8];
#pragma unroll
    for (int a = 0; a < 8; a++) gv[a] = *(const float4*)&Gs[ig + (a << 4)][h4];
#pragma unroll
    for (int b = 0; b < 8; b++) hv[b] = *(const float4*)&Hs[jg + (b << 4)][h4];
#pragma unroll
    for (int hh = 0; hh < 4; hh++)
#pragma unroll
      for (int a = 0; a < 8; a++) {
        float g = ((const float*)&gv[a])[hh];
#pragma unroll
        for (int b = 0; b < 8; b++) acc[a][b] += g * ((const float*)&hv[b])[hh];
      }
  }
#pragma unroll
  for (int a = 0; a < 8; a++) {
    float s = 0.f;
#pragma unroll
    for (int b = 0; b < 8; b++) s += expf(acc[a][b]);
    atomicAdd(&negs[ig + (a << 4)], s);
  }
  __syncthreads();
  if (t < 128) atomicAdd(&neg[i0 + t], negs[t]);
}

// ---------- ssl finalize ----------
__global__ __launch_bounds__(256) void sslfin_kernel(
    const float* __restrict__ gn, const float* __restrict__ hw,
    const float* __restrict__ neg, float* __restrict__ outp) {
  int gid = blockIdx.x * 256 + threadIdx.x;
  int w = gid >> 6, lane = gid & 63;
  if (w >= NB) return;
  float2 a = *(const float2*)(gn + (size_t)w * DD + 2 * lane);
  float2 b = *(const float2*)(hw + (size_t)w * DD + 2 * lane);
  float d = a.x * b.x + a.y * b.y;
#pragma unroll
  for (int o = 32; o > 0; o >>= 1) d += __shfl_down(d, o);
  if (lane == 0) {
    float pos = expf(d);
    float v = -logf(pos / (neg[w] + 1e-8f) + 1e-8f);
    atomicAdd(outp, v);
  }
}

extern "C" void kernel_launch(void* const* d_in, const int* in_sizes, int n_in,
                              void* d_out, int out_size, void* d_ws, size_t ws_size,
                              hipStream_t stream) {
  (void)in_sizes; (void)n_in; (void)out_size; (void)ws_size;
  const int* uids = (const int*)d_in[0];
  const int* iids = (const int*)d_in[1];
  const int* arow = (const int*)d_in[2];
  const int* acol = (const int*)d_in[3];
  const float* avals = (const float*)d_in[4];
  const float* uE = (const float*)d_in[5];
  const float* iE = (const float*)d_in[6];
  const float* uhy = (const float*)d_in[7];
  const float* ihy = (const float*)d_in[8];
  const float* Wu = (const float*)d_in[9];
  const float* Wi = (const float*)d_in[10];
  const float* Wt = (const float*)d_in[11];
  float* out = (float*)d_out;

  // workspace layout (~244 MB)
  float* p = (float*)d_ws;
  float* cur_u = p; p += (size_t)NU * DD;
  float* sum_u = p; p += (size_t)NU * DD;
  float* gnn_u = p; p += (size_t)NU * DD;
  float* cur_i = p; p += (size_t)NI * DD;
  float* sum_i = p; p += (size_t)NI * DD;
  float* gnn_i = p; p += (size_t)NI * DD;
  float* A_u = p; p += HH * DD;
  float* A_i = p; p += HH * DD;
  float* B_u = p; p += HH * DD;
  float* B_i = p; p += HH * DD;
  float* gg = p; p += (size_t)NB * DD;
  float* gh = p; p += (size_t)NB * DD;
  float* negb = p; p += 4 * NB;
  int* rowptr_u = (int*)p; p += NU + 1;
  int* cursor_u = (int*)p; p += NU;
  int* rowptr_i = (int*)p; p += NI + 1;
  int* cursor_i = (int*)p; p += NI;
  int* bsum = (int*)p; p += 256;
  int* eidx_u = (int*)p; p += NE;
  int* eidx_i = (int*)p; p += NE;

  const int GU = (NU + SCHUNK - 1) / SCHUNK;  // 49
  const int GI = (NI + SCHUNK - 1) / SCHUNK;  // 25
  const int EB = (NE + 255) / 256;

  // ---- CSR build (user side: sorted by arow; item side: sorted by acol) ----
  hipMemsetAsync(cursor_u, 0, NU * sizeof(int), stream);
  hist_kernel<<<EB, 256, 0, stream>>>(arow, cursor_u, NE);
  scan_bsum<<<GU, 256, 0, stream>>>(cursor_u, bsum, NU);
  scan_top<<<1, 256, 0, stream>>>(bsum, GU);
  scan_write<<<GU, 256, 0, stream>>>(cursor_u, bsum, rowptr_u, cursor_u, NU, NE);
  scatter_kernel<<<EB, 256, 0, stream>>>(arow, cursor_u, eidx_u, NE);

  hipMemsetAsync(cursor_i, 0, NI * sizeof(int), stream);
  hist_kernel<<<EB, 256, 0, stream>>>(acol, cursor_i, NE);
  scan_bsum<<<GI, 256, 0, stream>>>(cursor_i, bsum, NI);
  scan_top<<<1, 256, 0, stream>>>(bsum, GI);
  scan_write<<<GI, 256, 0, stream>>>(cursor_i, bsum, rowptr_i, cursor_i, NI, NE);
  scatter_kernel<<<EB, 256, 0, stream>>>(acol, cursor_i, eidx_i, NE);

  hipMemcpyAsync(cur_u, uE, (size_t)NU * DD * 4, hipMemcpyDeviceToDevice, stream);
  hipMemcpyAsync(sum_u, uE, (size_t)NU * DD * 4, hipMemcpyDeviceToDevice, stream);
  hipMemcpyAsync(cur_i, iE, (size_t)NI * DD * 4, hipMemcpyDeviceToDevice, stream);
  hipMemcpyAsync(sum_i, iE, (size_t)NI * DD * 4, hipMemcpyDeviceToDevice, stream);
  hipMemsetAsync(out + NB, 0, 2 * sizeof(float), stream);
  hipMemsetAsync(negb, 0, 4 * NB * sizeof(float), stream);

  for (int l = 0; l < 2; l++) {
    const float* Wt_l = Wt + (size_t)l * DD * DD;
    hipMemsetAsync(A_u, 0, 2 * HH * DD * 4, stream);  // A_u + A_i contiguous
    spmm_csr_kernel<<<NU / 4, 256, 0, stream>>>(rowptr_u, eidx_u, acol, avals, cur_i, gnn_u, NU);
    spmm_csr_kernel<<<NI / 4, 256, 0, stream>>>(rowptr_i, eidx_i, arow, avals, cur_u, gnn_i, NI);
    atb_kernel<<<512, 256, 0, stream>>>(uE, cur_u, A_u, NU);
    atb_kernel<<<512, 256, 0, stream>>>(iE, cur_i, A_i, NI);
    chain_kernel<<<16, 256, 0, stream>>>(A_u, A_i, uhy, ihy,
        Wu + (size_t)l * 3 * HH * HH, Wi + (size_t)l * 3 * HH * HH, B_u, B_i);

    // ---- user side ----
    sslgath_kernel<<<NB, 128, 0, stream>>>(uids, gnn_u, uE, B_u, gg, gh);
    nmul_upd_kernel<<<512, 256, 0, stream>>>(uE, B_u, gnn_u, cur_u, sum_u, NU);
    xform_kernel<<<NB, 128, 0, stream>>>(gh, gg, Wt_l);
    gram_kernel<<<dim3(NB / 128, NB / 128), 256, 0, stream>>>(gg, gh, negb + (2 * l) * NB);
    sslfin_kernel<<<NB / 4, 256, 0, stream>>>(gg, gh, negb + (2 * l) * NB, out + NB);

    // ---- item side ----
    sslgath_kernel<<<NB, 128, 0, stream>>>(iids, gnn_i, iE, B_i, gg, gh);
    nmul_upd_kernel<<<512, 256, 0, stream>>>(iE, B_i, gnn_i, cur_i, sum_i, NI);
    xform_kernel<<<NB, 128, 0, stream>>>(gh, gg, Wt_l);
    gram_kernel<<<dim3(NB / 128, NB / 128), 256, 0, stream>>>(gg, gh, negb + (2 * l + 1) * NB);
    sslfin_kernel<<<NB / 4, 256, 0, stream>>>(gg, gh, negb + (2 * l + 1) * NB, out + NB);
  }

  preds_kernel<<<NB / 4, 256, 0, stream>>>(uids, iids, sum_u, sum_i, out);
  sumsq_kernel<<<2048, 256, 0, stream>>>(uE, NU * DD, out + NB + 1);
  sumsq_kernel<<<1024, 256, 0, stream>>>(iE, NI * DD, out + NB + 1);
  sumsq_kernel<<<64, 256, 0, stream>>>(uhy, DD * HH, out + NB + 1);
  sumsq_kernel<<<64, 256, 0, stream>>>(ihy, DD * HH, out + NB + 1);
}

// Round 5
// 2389.585 us; speedup vs baseline: 2.8354x; 1.5076x over previous
//
#include <hip/hip_runtime.h>

#define NU 100000
#define NI 50000
#define DD 128
#define HH 128
#define NE 1000000
#define NB 4096
#define SCHUNK 2048
#define ATBB 512

__device__ __forceinline__ float lk(float x) { return fmaxf(0.5f * x, x); }

// ================= CSR build =================
__global__ __launch_bounds__(256) void hist_kernel(const int* __restrict__ idx,
                                                   int* __restrict__ deg, int n) {
  int e = blockIdx.x * 256 + threadIdx.x;
  if (e < n) atomicAdd(&deg[idx[e]], 1);
}

__global__ __launch_bounds__(256) void scan_bsum(const int* __restrict__ deg,
                                                 int* __restrict__ bsum, int N) {
  int b = blockIdx.x, t = threadIdx.x;
  int base = b * SCHUNK;
  int s = 0;
  for (int i = t; i < SCHUNK; i += 256) {
    int g = base + i;
    if (g < N) s += deg[g];
  }
#pragma unroll
  for (int o = 32; o > 0; o >>= 1) s += __shfl_down(s, o);
  __shared__ int ws[4];
  if ((t & 63) == 0) ws[t >> 6] = s;
  __syncthreads();
  if (t == 0) bsum[b] = ws[0] + ws[1] + ws[2] + ws[3];
}

__global__ __launch_bounds__(256) void scan_top(int* __restrict__ bsum, int G) {
  int t = threadIdx.x;
  __shared__ int sh[256];
  int v = (t < G) ? bsum[t] : 0;
  sh[t] = v;
  __syncthreads();
  for (int o = 1; o < 256; o <<= 1) {
    int add = (t >= o) ? sh[t - o] : 0;
    __syncthreads();
    sh[t] += add;
    __syncthreads();
  }
  if (t < G) bsum[t] = sh[t] - v;  // exclusive
}

// deg may alias cursor: each element read+written only by its owning thread.
__global__ __launch_bounds__(256) void scan_write(const int* __restrict__ deg,
                                                  const int* __restrict__ bsumx,
                                                  int* __restrict__ rowptr,
                                                  int* __restrict__ cursor,
                                                  int N, int total) {
  int b = blockIdx.x, t = threadIdx.x;
  int base = b * SCHUNK + t * 8;
  int v[8], s = 0;
#pragma unroll
  for (int i = 0; i < 8; i++) {
    int g = base + i;
    v[i] = (g < N) ? deg[g] : 0;
    s += v[i];
  }
  __shared__ int sh[256];
  sh[t] = s;
  __syncthreads();
  for (int o = 1; o < 256; o <<= 1) {
    int add = (t >= o) ? sh[t - o] : 0;
    __syncthreads();
    sh[t] += add;
    __syncthreads();
  }
  int off = bsumx[b] + sh[t] - s;
#pragma unroll
  for (int i = 0; i < 8; i++) {
    int g = base + i;
    if (g < N) { rowptr[g] = off; cursor[g] = off; }
    off += v[i];
  }
  if (b == 0 && t == 0) rowptr[N] = total;
}

// scatter sorted col/val arrays directly (kills one indirection level in spmm)
__global__ __launch_bounds__(256) void scatter_kernel(const int* __restrict__ idx,
                                                      const int* __restrict__ other,
                                                      const float* __restrict__ vals,
                                                      int* __restrict__ cursor,
                                                      int* __restrict__ scol,
                                                      float* __restrict__ sval, int n) {
  int e = blockIdx.x * 256 + threadIdx.x;
  if (e < n) {
    int p = atomicAdd(&cursor[idx[e]], 1);
    scol[p] = other[e];
    sval[p] = vals[e];
  }
}

// ================= spmm: wave per row, 2 half-waves x float4, 4 gathers in flight ====
__global__ __launch_bounds__(256) void spmm_csr_kernel(
    const int* __restrict__ rowptr, const int* __restrict__ scol,
    const float* __restrict__ sval, const float* __restrict__ x,
    float* __restrict__ y, int N) {
  int w = (blockIdx.x * 256 + threadIdx.x) >> 6;
  if (w >= N) return;
  int lane = threadIdx.x & 63;
  int half = lane >> 5, l32 = lane & 31;
  const float4* x4 = (const float4*)x;
  int j0 = rowptr[w], j1 = rowptr[w + 1];
  float ax = 0.f, ay = 0.f, az = 0.f, aw = 0.f;
  int j = j0 + half;
  for (; j + 2 < j1; j += 4) {
    int c0 = scol[j], c1 = scol[j + 2];
    float v0 = sval[j], v1 = sval[j + 2];
    float4 x0 = x4[(size_t)c0 * 32 + l32];
    float4 x1 = x4[(size_t)c1 * 32 + l32];
    ax += v0 * x0.x + v1 * x1.x;
    ay += v0 * x0.y + v1 * x1.y;
    az += v0 * x0.z + v1 * x1.z;
    aw += v0 * x0.w + v1 * x1.w;
  }
  for (; j < j1; j += 2) {
    int c0 = scol[j];
    float v0 = sval[j];
    float4 x0 = x4[(size_t)c0 * 32 + l32];
    ax += v0 * x0.x; ay += v0 * x0.y; az += v0 * x0.z; aw += v0 * x0.w;
  }
  ax += __shfl_xor(ax, 32); ay += __shfl_xor(ay, 32);
  az += __shfl_xor(az, 32); aw += __shfl_xor(aw, 32);
  if (half == 0) {
    float4 r; r.x = ax; r.y = ay; r.z = az; r.w = aw;
    ((float4*)y)[(size_t)w * 32 + l32] = r;
  }
}

// ====== A = E^T @ X: 64-row K-tiles, {4j,4j+64} fragments, plain partial writes ======
__global__ __launch_bounds__(256) void atb_kernel(
    const float* __restrict__ E, const float* __restrict__ X,
    float* __restrict__ part, int N) {
  __shared__ __align__(16) float Es[64][132];
  __shared__ __align__(16) float Xs[64][132];
  int t = threadIdx.x;
  int ip = (t >> 4) << 2;   // rows ip+{0..3}, +64
  int jp = (t & 15) << 2;   // cols jp+{0..3}, +64
  int rpb = (N + (int)gridDim.x - 1) / (int)gridDim.x;
  int n0 = blockIdx.x * rpb;
  int n1 = min(n0 + rpb, N);
  float acc[2][2][4][4] = {};
  const float4* E4 = (const float4*)E;
  const float4* X4 = (const float4*)X;
  for (int n = n0; n < n1; n += 64) {
    int nr = min(64, n1 - n);
    __syncthreads();
#pragma unroll
    for (int q = 0; q < 8; q++) {
      int f = t + (q << 8);
      int row = f >> 5, c4 = f & 31;
      float4 ev = {0.f, 0.f, 0.f, 0.f}, xv = {0.f, 0.f, 0.f, 0.f};
      if (row < nr) {
        size_t gi = (size_t)(n + row) * 32 + c4;
        ev = E4[gi]; xv = X4[gi];
      }
      *(float4*)&Es[row][c4 << 2] = ev;
      *(float4*)&Xs[row][c4 << 2] = xv;
    }
    __syncthreads();
#pragma unroll 2
    for (int rr = 0; rr < 64; rr++) {
      float4 e0 = *(const float4*)&Es[rr][ip];
      float4 e1 = *(const float4*)&Es[rr][ip + 64];
      float4 x0 = *(const float4*)&Xs[rr][jp];
      float4 x1 = *(const float4*)&Xs[rr][jp + 64];
      const float* e0p = (const float*)&e0;
      const float* e1p = (const float*)&e1;
      const float* x0p = (const float*)&x0;
      const float* x1p = (const float*)&x1;
#pragma unroll
      for (int ai = 0; ai < 4; ai++)
#pragma unroll
        for (int aj = 0; aj < 4; aj++) {
          acc[0][0][ai][aj] += e0p[ai] * x0p[aj];
          acc[0][1][ai][aj] += e0p[ai] * x1p[aj];
          acc[1][0][ai][aj] += e1p[ai] * x0p[aj];
          acc[1][1][ai][aj] += e1p[ai] * x1p[aj];
        }
    }
  }
  float* dst = part + (size_t)blockIdx.x * 16384;
#pragma unroll
  for (int rh = 0; rh < 2; rh++)
#pragma unroll
    for (int ai = 0; ai < 4; ai++) {
      int row = rh * 64 + ip + ai;
#pragma unroll
      for (int ch = 0; ch < 2; ch++) {
        float4 v;
        v.x = acc[rh][ch][ai][0]; v.y = acc[rh][ch][ai][1];
        v.z = acc[rh][ch][ai][2]; v.w = acc[rh][ch][ai][3];
        *(float4*)&dst[row * 128 + ch * 64 + jp] = v;
      }
    }
}

__global__ __launch_bounds__(256) void reduce_atb_kernel(
    const float* __restrict__ part, float* __restrict__ A) {
  int e4 = blockIdx.x * 256 + threadIdx.x;  // 0..4095 float4 elements
  const float4* p4 = (const float4*)part;
  float4 s = {0.f, 0.f, 0.f, 0.f};
#pragma unroll 4
  for (int b = 0; b < ATBB; b++) {
    float4 v = p4[(size_t)b * 4096 + e4];
    s.x += v.x; s.y += v.y; s.z += v.z; s.w += v.w;
  }
  ((float4*)A)[e4] = s;
}

// ---------- chain: column-strip parallel, W staged in LDS ----------
__global__ __launch_bounds__(256) void chain_kernel(
    const float* __restrict__ A_u, const float* __restrict__ A_i,
    const float* __restrict__ uhy, const float* __restrict__ ihy,
    const float* __restrict__ Wu_l, const float* __restrict__ Wi_l,
    float* __restrict__ B_u, float* __restrict__ B_i) {
  __shared__ float Wb[128 * 132];
  __shared__ float LA[128][16];
  __shared__ float LB[128][16];
  int side = blockIdx.x >> 3, strip = blockIdx.x & 7;
  const float* A = side ? A_i : A_u;
  const float* hy = side ? ihy : uhy;
  const float* W = side ? Wi_l : Wu_l;
  float* Bo = side ? B_i : B_u;
  int t = threadIdx.x;
  int j0 = strip * 16;
  for (int i = t; i < 2048; i += 256) LA[i >> 4][i & 15] = A[(i >> 4) * 128 + j0 + (i & 15)];
  for (int i = t; i < 16384; i += 256) Wb[(i >> 7) * 132 + (i & 127)] = hy[i];
  __syncthreads();
  int jc = t & 15, i0 = (t >> 4) * 8;
  {
    float acc[8] = {};
    for (int k = 0; k < 128; k++) {
      float lv = LA[k][jc];
      const float* wr = &Wb[k * 132 + i0];
#pragma unroll
      for (int a = 0; a < 8; a++) acc[a] += wr[a] * lv;
    }
#pragma unroll
    for (int a = 0; a < 8; a++) LB[i0 + a][jc] = lk(acc[a]);
  }
  __syncthreads();
  float (*pin)[16] = LB;
  float (*pout)[16] = LA;
  for (int s = 0; s < 3; s++) {
    for (int i = t; i < 16384; i += 256) Wb[(i >> 7) * 132 + (i & 127)] = W[s * 16384 + i];
    __syncthreads();
    float acc[8] = {};
    for (int k = 0; k < 128; k++) {
      float lv = pin[k][jc];
      const float* wr = &Wb[k * 132 + i0];
#pragma unroll
      for (int a = 0; a < 8; a++) acc[a] += wr[a] * lv;
    }
#pragma unroll
    for (int a = 0; a < 8; a++) pout[i0 + a][jc] = lk(acc[a]) + pin[i0 + a][jc];
    __syncthreads();
    float (*tmp)[16] = pin; pin = pout; pout = tmp;
  }
  for (int i = t; i < 16384; i += 256) Wb[(i >> 7) * 132 + (i & 127)] = hy[i];
  __syncthreads();
  {
    int i = t >> 1, jb = (t & 1) * 8;
    float acc[8] = {};
    for (int k = 0; k < 128; k++) {
      float hv = Wb[i * 132 + k];
      const float* lr = &pin[k][jb];
#pragma unroll
      for (int b = 0; b < 8; b++) acc[b] += hv * lr[b];
    }
#pragma unroll
    for (int b = 0; b < 8; b++) Bo[i * 128 + j0 + jb + b] = acc[b];
  }
}

// ---------- fused: h=leaky(E@B); cur += leaky(gnn)+h ----------
__global__ __launch_bounds__(256) void nmul_upd_kernel(
    const float* __restrict__ E, const float* __restrict__ Bm,
    const float* __restrict__ gnn, float* __restrict__ cur, int N) {
  __shared__ __align__(16) float Bs[128][132];
  __shared__ __align__(16) float Es[128][132];
  int t = threadIdx.x;
  int rg = t >> 4, dg = t & 15;
  for (int k = t; k < 16384; k += 256) Bs[k >> 7][k & 127] = Bm[k];
  int ntiles = (N + 127) >> 7;
  for (int tile = blockIdx.x; tile < ntiles; tile += gridDim.x) {
    int n0 = tile << 7;
    int nr = min(128, N - n0);
    __syncthreads();
    for (int k = t; k < 16384; k += 256) {
      int rr = k >> 7, cc = k & 127;
      Es[rr][cc] = (rr < nr) ? E[(size_t)(n0 + rr) * DD + cc] : 0.f;
    }
    __syncthreads();
    float acc[8][8] = {};
    for (int h4 = 0; h4 < 128; h4 += 4) {
      float4 ev[8];
#pragma unroll
      for (int a = 0; a < 8; a++) ev[a] = *(const float4*)&Es[rg + (a << 4)][h4];
#pragma unroll
      for (int hh = 0; hh < 4; hh++) {
        float4 b0 = *(const float4*)&Bs[h4 + hh][dg << 2];
        float4 b1 = *(const float4*)&Bs[h4 + hh][(dg << 2) + 64];
#pragma unroll
        for (int a = 0; a < 8; a++) {
          float e = ((const float*)&ev[a])[hh];
          acc[a][0] += e * b0.x; acc[a][1] += e * b0.y;
          acc[a][2] += e * b0.z; acc[a][3] += e * b0.w;
          acc[a][4] += e * b1.x; acc[a][5] += e * b1.y;
          acc[a][6] += e * b1.z; acc[a][7] += e * b1.w;
        }
      }
    }
#pragma unroll
    for (int a = 0; a < 8; a++) {
      int n = n0 + rg + (a << 4);
      if (n < N) {
        size_t base = (size_t)n * DD + (dg << 2);
        float4 g0 = *(const float4*)(gnn + base);
        float4 g1 = *(const float4*)(gnn + base + 64);
        float4 c0 = *(const float4*)(cur + base);
        float4 c1 = *(const float4*)(cur + base + 64);
        c0.x += lk(g0.x) + lk(acc[a][0]); c0.y += lk(g0.y) + lk(acc[a][1]);
        c0.z += lk(g0.z) + lk(acc[a][2]); c0.w += lk(g0.w) + lk(acc[a][3]);
        c1.x += lk(g1.x) + lk(acc[a][4]); c1.y += lk(g1.y) + lk(acc[a][5]);
        c1.z += lk(g1.z) + lk(acc[a][6]); c1.w += lk(g1.w) + lk(acc[a][7]);
        *(float4*)(cur + base) = c0; *(float4*)(cur + base + 64) = c1;
      }
    }
  }
}

// ---------- ssl gather, batched: 32 ids/block, B staged once ----------
__global__ __launch_bounds__(128) void sslgath_kernel(
    const int* __restrict__ ids, const float* __restrict__ gnn,
    const float* __restrict__ E, const float* __restrict__ Bm,
    float* __restrict__ og, float* __restrict__ oh) {
  __shared__ __align__(16) float Bs[128][132];
  __shared__ __align__(16) float Eb[32][132];
  __shared__ int idb[32];
  int t = threadIdx.x;
  int base = blockIdx.x * 32;
  if (t < 32) idb[t] = ids[base + t];
#pragma unroll
  for (int q = 0; q < 32; q++) {
    int f = t + q * 128;
    *(float4*)&Bs[f >> 5][(f & 31) << 2] = ((const float4*)Bm)[f];
  }
  __syncthreads();
#pragma unroll
  for (int q = 0; q < 8; q++) {
    int f = t + q * 128;
    int r = f >> 5, c4 = f & 31;
    *(float4*)&Eb[r][c4 << 2] = ((const float4*)E)[(size_t)idb[r] * 32 + c4];
  }
  __syncthreads();
  float acc[32] = {};
  for (int k = 0; k < 128; k++) {
    float b = Bs[k][t];
#pragma unroll
    for (int r = 0; r < 32; r++) acc[r] += Eb[r][k] * b;
  }
  for (int r = 0; r < 32; r++) {
    int id = idb[r];
    og[(size_t)(base + r) * DD + t] = lk(gnn[(size_t)id * DD + t]);
    oh[(size_t)(base + r) * DD + t] = lk(acc[r]);
  }
}

// ---------- layer-sum accumulation on gathered rows only ----------
__global__ __launch_bounds__(128) void gaccum_kernel(
    const int* __restrict__ ids, const float* __restrict__ cur,
    float* __restrict__ sumg) {
  int b = blockIdx.x, d = threadIdx.x;
  int id = ids[b];
  sumg[(size_t)b * DD + d] += cur[(size_t)id * DD + d];
}

// ---------- preds from gathered sums ----------
__global__ __launch_bounds__(256) void preds_kernel(
    const float* __restrict__ su, const float* __restrict__ si,
    float* __restrict__ outp) {
  int gid = blockIdx.x * 256 + threadIdx.x;
  int w = gid >> 6, lane = gid & 63;
  if (w >= NB) return;
  float2 a = *(const float2*)(su + (size_t)w * DD + 2 * lane);
  float2 b = *(const float2*)(si + (size_t)w * DD + 2 * lane);
  float d = a.x * b.x + a.y * b.y;
#pragma unroll
  for (int o = 32; o > 0; o >>= 1) d += __shfl_down(d, o);
  if (lane == 0) outp[w] = d;
}

// ---------- sum of squares (reg) ----------
__global__ __launch_bounds__(256) void sumsq_kernel(
    const float* __restrict__ x, int n, float* __restrict__ outp) {
  float acc = 0.f;
  for (int i = blockIdx.x * 256 + threadIdx.x; i < n; i += gridDim.x * 256) {
    float v = x[i];
    acc += v * v;
  }
#pragma unroll
  for (int o = 32; o > 0; o >>= 1) acc += __shfl_down(acc, o);
  __shared__ float s[4];
  if ((threadIdx.x & 63) == 0) s[threadIdx.x >> 6] = acc;
  __syncthreads();
  if (threadIdx.x == 0) atomicAdd(outp, s[0] + s[1] + s[2] + s[3]);
}

// ---------- row l2-normalize: gg in place, gh -> hn ----------
__global__ __launch_bounds__(128) void norm_kernel(
    const float* __restrict__ gh, float* __restrict__ gg,
    float* __restrict__ hn) {
  int r = blockIdx.x, d = threadIdx.x;
  __shared__ float red[4];
  float hv = gh[(size_t)r * DD + d];
  float gv = gg[(size_t)r * DD + d];
  float h2 = hv * hv, g2 = gv * gv;
#pragma unroll
  for (int o = 32; o > 0; o >>= 1) { h2 += __shfl_down(h2, o); g2 += __shfl_down(g2, o); }
  if ((d & 63) == 0) { red[(d >> 6) * 2] = h2; red[(d >> 6) * 2 + 1] = g2; }
  __syncthreads();
  float hnorm = sqrtf(red[0] + red[2]);
  float gnorm = sqrtf(red[1] + red[3]);
  hn[(size_t)r * DD + d] = hv / fmaxf(hnorm, 1e-12f);
  gg[(size_t)r * DD + d] = gv / fmaxf(gnorm, 1e-12f);
}

// ---------- out[4096,128] = In @ W (tiled, W staged once per 128-row tile) ----------
__global__ __launch_bounds__(256) void nmul_plain_kernel(
    const float* __restrict__ In, const float* __restrict__ Wm,
    float* __restrict__ outp) {
  __shared__ __align__(16) float Bs[128][132];
  __shared__ __align__(16) float Es[128][132];
  int t = threadIdx.x;
  int rg = t >> 4, dg = t & 15;
  int n0 = blockIdx.x << 7;
  for (int k = t; k < 16384; k += 256) {
    Bs[k >> 7][k & 127] = Wm[k];
    Es[k >> 7][k & 127] = In[(size_t)n0 * DD + k];
  }
  __syncthreads();
  float acc[8][8] = {};
  for (int h4 = 0; h4 < 128; h4 += 4) {
    float4 ev[8];
#pragma unroll
    for (int a = 0; a < 8; a++) ev[a] = *(const float4*)&Es[rg + (a << 4)][h4];
#pragma unroll
    for (int hh = 0; hh < 4; hh++) {
      float4 b0 = *(const float4*)&Bs[h4 + hh][dg << 2];
      float4 b1 = *(const float4*)&Bs[h4 + hh][(dg << 2) + 64];
#pragma unroll
      for (int a = 0; a < 8; a++) {
        float e = ((const float*)&ev[a])[hh];
        acc[a][0] += e * b0.x; acc[a][1] += e * b0.y;
        acc[a][2] += e * b0.z; acc[a][3] += e * b0.w;
        acc[a][4] += e * b1.x; acc[a][5] += e * b1.y;
        acc[a][6] += e * b1.z; acc[a][7] += e * b1.w;
      }
    }
  }
#pragma unroll
  for (int a = 0; a < 8; a++) {
    size_t base = (size_t)(n0 + rg + (a << 4)) * DD + (dg << 2);
    float4 v0, v1;
    v0.x = acc[a][0]; v0.y = acc[a][1]; v0.z = acc[a][2]; v0.w = acc[a][3];
    v1.x = acc[a][4]; v1.y = acc[a][5]; v1.z = acc[a][6]; v1.w = acc[a][7];
    *(float4*)(outp + base) = v0;
    *(float4*)(outp + base + 64) = v1;
  }
}

// ---------- gram: neg[i] += sum_j exp(gn_i . hw_j), transposed H staging ----------
__global__ __launch_bounds__(256) void gram_kernel(
    const float* __restrict__ gn, const float* __restrict__ hw,
    float* __restrict__ neg) {
  __shared__ __align__(16) float Gs[128][132];
  __shared__ __align__(16) float Ht[128][132];  // Ht[k][j] = hw[j0+j][k]
  int t = threadIdx.x;
  int rg = t >> 4, jp = (t & 15) << 2;
  int i0 = blockIdx.x << 7, j0 = blockIdx.y << 7;
  for (int k = t; k < 16384; k += 256) {
    int rr = k >> 7, cc = k & 127;
    Gs[rr][cc] = gn[(size_t)(i0 + rr) * DD + cc];
    Ht[cc][rr] = hw[(size_t)(j0 + rr) * DD + cc];
  }
  __syncthreads();
  float acc[8][8] = {};
  for (int h4 = 0; h4 < 128; h4 += 4) {
    float4 ev[8];
#pragma unroll
    for (int a = 0; a < 8; a++) ev[a] = *(const float4*)&Gs[rg + (a << 4)][h4];
#pragma unroll
    for (int hh = 0; hh < 4; hh++) {
      float4 b0 = *(const float4*)&Ht[h4 + hh][jp];
      float4 b1 = *(const float4*)&Ht[h4 + hh][jp + 64];
#pragma unroll
      for (int a = 0; a < 8; a++) {
        float g = ((const float*)&ev[a])[hh];
        acc[a][0] += g * b0.x; acc[a][1] += g * b0.y;
        acc[a][2] += g * b0.z; acc[a][3] += g * b0.w;
        acc[a][4] += g * b1.x; acc[a][5] += g * b1.y;
        acc[a][6] += g * b1.z; acc[a][7] += g * b1.w;
      }
    }
  }
#pragma unroll
  for (int a = 0; a < 8; a++) {
    float s = 0.f;
#pragma unroll
    for (int b = 0; b < 8; b++) s += expf(acc[a][b]);
    s += __shfl_xor(s, 1);
    s += __shfl_xor(s, 2);
    s += __shfl_xor(s, 4);
    s += __shfl_xor(s, 8);
    if ((t & 15) == 0) atomicAdd(&neg[i0 + rg + (a << 4)], s);
  }
}

// ---------- ssl finalize ----------
__global__ __launch_bounds__(256) void sslfin_kernel(
    const float* __restrict__ gn, const float* __restrict__ hw,
    const float* __restrict__ neg, float* __restrict__ outp) {
  int gid = blockIdx.x * 256 + threadIdx.x;
  int w = gid >> 6, lane = gid & 63;
  if (w >= NB) return;
  float2 a = *(const float2*)(gn + (size_t)w * DD + 2 * lane);
  float2 b = *(const float2*)(hw + (size_t)w * DD + 2 * lane);
  float d = a.x * b.x + a.y * b.y;
#pragma unroll
  for (int o = 32; o > 0; o >>= 1) d += __shfl_down(d, o);
  if (lane == 0) {
    float pos = expf(d);
    float v = -logf(pos / (neg[w] + 1e-8f) + 1e-8f);
    atomicAdd(outp, v);
  }
}

extern "C" void kernel_launch(void* const* d_in, const int* in_sizes, int n_in,
                              void* d_out, int out_size, void* d_ws, size_t ws_size,
                              hipStream_t stream) {
  (void)in_sizes; (void)n_in; (void)out_size; (void)ws_size;
  const int* uids = (const int*)d_in[0];
  const int* iids = (const int*)d_in[1];
  const int* arow = (const int*)d_in[2];
  const int* acol = (const int*)d_in[3];
  const float* avals = (const float*)d_in[4];
  const float* uE = (const float*)d_in[5];
  const float* iE = (const float*)d_in[6];
  const float* uhy = (const float*)d_in[7];
  const float* ihy = (const float*)d_in[8];
  const float* Wu = (const float*)d_in[9];
  const float* Wi = (const float*)d_in[10];
  const float* Wt = (const float*)d_in[11];
  float* out = (float*)d_out;

  // workspace layout (~209 MB)
  float* p = (float*)d_ws;
  float* cur_u = p; p += (size_t)NU * DD;
  float* gnn_u = p; p += (size_t)NU * DD;
  float* cur_i = p; p += (size_t)NI * DD;
  float* gnn_i = p; p += (size_t)NI * DD;
  float* A_u = p; p += HH * DD;
  float* A_i = p; p += HH * DD;
  float* B_u = p; p += HH * DD;
  float* B_i = p; p += HH * DD;
  float* sumg_u = p; p += (size_t)NB * DD;
  float* sumg_i = p; p += (size_t)NB * DD;
  float* region = p; p += (size_t)ATBB * 16384;  // Apart ∪ {gg, gh, hn}
  float* negb = p; p += 4 * NB;
  int* rowptr_u = (int*)p; p += NU + 1;
  int* cursor_u = (int*)p; p += NU;
  int* rowptr_i = (int*)p; p += NI + 1;
  int* cursor_i = (int*)p; p += NI;
  int* bsum = (int*)p; p += 256;
  int* scol_u = (int*)p; p += NE;
  float* sval_u = p; p += NE;
  int* scol_i = (int*)p; p += NE;
  float* sval_i = p; p += NE;

  float* Apart = region;
  float* gg = region;
  float* gh = region + (size_t)NB * DD;
  float* hn = region + 2 * (size_t)NB * DD;

  const int GU = (NU + SCHUNK - 1) / SCHUNK;
  const int GI = (NI + SCHUNK - 1) / SCHUNK;
  const int EB = (NE + 255) / 256;

  // ---- CSR build ----
  hipMemsetAsync(cursor_u, 0, NU * sizeof(int), stream);
  hist_kernel<<<EB, 256, 0, stream>>>(arow, cursor_u, NE);
  scan_bsum<<<GU, 256, 0, stream>>>(cursor_u, bsum, NU);
  scan_top<<<1, 256, 0, stream>>>(bsum, GU);
  scan_write<<<GU, 256, 0, stream>>>(cursor_u, bsum, rowptr_u, cursor_u, NU, NE);
  scatter_kernel<<<EB, 256, 0, stream>>>(arow, acol, avals, cursor_u, scol_u, sval_u, NE);

  hipMemsetAsync(cursor_i, 0, NI * sizeof(int), stream);
  hist_kernel<<<EB, 256, 0, stream>>>(acol, cursor_i, NE);
  scan_bsum<<<GI, 256, 0, stream>>>(cursor_i, bsum, NI);
  scan_top<<<1, 256, 0, stream>>>(bsum, GI);
  scan_write<<<GI, 256, 0, stream>>>(cursor_i, bsum, rowptr_i, cursor_i, NI, NE);
  scatter_kernel<<<EB, 256, 0, stream>>>(acol, arow, avals, cursor_i, scol_i, sval_i, NE);

  hipMemcpyAsync(cur_u, uE, (size_t)NU * DD * 4, hipMemcpyDeviceToDevice, stream);
  hipMemcpyAsync(cur_i, iE, (size_t)NI * DD * 4, hipMemcpyDeviceToDevice, stream);
  hipMemsetAsync(out + NB, 0, 2 * sizeof(float), stream);
  hipMemsetAsync(negb, 0, 4 * NB * sizeof(float), stream);
  hipMemsetAsync(sumg_u, 0, 2 * (size_t)NB * DD * 4, stream);  // sumg_u + sumg_i
  gaccum_kernel<<<NB, 128, 0, stream>>>(uids, uE, sumg_u);
  gaccum_kernel<<<NB, 128, 0, stream>>>(iids, iE, sumg_i);

  for (int l = 0; l < 2; l++) {
    const float* Wt_l = Wt + (size_t)l * DD * DD;
    spmm_csr_kernel<<<NU / 4, 256, 0, stream>>>(rowptr_u, scol_u, sval_u, cur_i, gnn_u, NU);
    spmm_csr_kernel<<<NI / 4, 256, 0, stream>>>(rowptr_i, scol_i, sval_i, cur_u, gnn_i, NI);
    atb_kernel<<<ATBB, 256, 0, stream>>>(uE, cur_u, Apart, NU);
    reduce_atb_kernel<<<16, 256, 0, stream>>>(Apart, A_u);
    atb_kernel<<<ATBB, 256, 0, stream>>>(iE, cur_i, Apart, NI);
    reduce_atb_kernel<<<16, 256, 0, stream>>>(Apart, A_i);
    chain_kernel<<<16, 256, 0, stream>>>(A_u, A_i, uhy, ihy,
        Wu + (size_t)l * 3 * HH * HH, Wi + (size_t)l * 3 * HH * HH, B_u, B_i);

    // ---- user side ----
    sslgath_kernel<<<NB / 32, 128, 0, stream>>>(uids, gnn_u, uE, B_u, gg, gh);
    nmul_upd_kernel<<<512, 256, 0, stream>>>(uE, B_u, gnn_u, cur_u, NU);
    gaccum_kernel<<<NB, 128, 0, stream>>>(uids, cur_u, sumg_u);
    norm_kernel<<<NB, 128, 0, stream>>>(gh, gg, hn);
    nmul_plain_kernel<<<NB / 128, 256, 0, stream>>>(hn, Wt_l, gh);
    gram_kernel<<<dim3(NB / 128, NB / 128), 256, 0, stream>>>(gg, gh, negb + (2 * l) * NB);
    sslfin_kernel<<<NB / 4, 256, 0, stream>>>(gg, gh, negb + (2 * l) * NB, out + NB);

    // ---- item side ----
    sslgath_kernel<<<NB / 32, 128, 0, stream>>>(iids, gnn_i, iE, B_i, gg, gh);
    nmul_upd_kernel<<<512, 256, 0, stream>>>(iE, B_i, gnn_i, cur_i, NI);
    gaccum_kernel<<<NB, 128, 0, stream>>>(iids, cur_i, sumg_i);
    norm_kernel<<<NB, 128, 0, stream>>>(gh, gg, hn);
    nmul_plain_kernel<<<NB / 128, 256, 0, stream>>>(hn, Wt_l, gh);
    gram_kernel<<<dim3(NB / 128, NB / 128), 256, 0, stream>>>(gg, gh, negb + (2 * l + 1) * NB);
    sslfin_kernel<<<NB / 4, 256, 0, stream>>>(gg, gh, negb + (2 * l + 1) * NB, out + NB);
  }

  preds_kernel<<<NB / 4, 256, 0, stream>>>(sumg_u, sumg_i, out);
  sumsq_kernel<<<2048, 256, 0, stream>>>(uE, NU * DD, out + NB + 1);
  sumsq_kernel<<<1024, 256, 0, stream>>>(iE, NI * DD, out + NB + 1);
  sumsq_kernel<<<64, 256, 0, stream>>>(uhy, DD * HH, out + NB + 1);
  sumsq_kernel<<<64, 256, 0, stream>>>(ihy, DD * HH, out + NB + 1);
}

// Round 6
// 2217.188 us; speedup vs baseline: 3.0559x; 1.0778x over previous
//
#include <hip/hip_runtime.h>

#define NU 100000
#define NI 50000
#define DD 128
#define HH 128
#define NE 1000000
#define NB 4096
#define SCHUNK 2048
#define ATBB 512

__device__ __forceinline__ float lk(float x) { return fmaxf(0.5f * x, x); }

// ================= CSR build =================
__global__ __launch_bounds__(256) void hist_kernel(const int* __restrict__ idx,
                                                   int* __restrict__ deg, int n) {
  int e = blockIdx.x * 256 + threadIdx.x;
  if (e < n) atomicAdd(&deg[idx[e]], 1);
}

__global__ __launch_bounds__(256) void scan_bsum(const int* __restrict__ deg,
                                                 int* __restrict__ bsum, int N) {
  int b = blockIdx.x, t = threadIdx.x;
  int base = b * SCHUNK;
  int s = 0;
  for (int i = t; i < SCHUNK; i += 256) {
    int g = base + i;
    if (g < N) s += deg[g];
  }
#pragma unroll
  for (int o = 32; o > 0; o >>= 1) s += __shfl_down(s, o);
  __shared__ int ws[4];
  if ((t & 63) == 0) ws[t >> 6] = s;
  __syncthreads();
  if (t == 0) bsum[b] = ws[0] + ws[1] + ws[2] + ws[3];
}

__global__ __launch_bounds__(256) void scan_top(int* __restrict__ bsum, int G) {
  int t = threadIdx.x;
  __shared__ int sh[256];
  int v = (t < G) ? bsum[t] : 0;
  sh[t] = v;
  __syncthreads();
  for (int o = 1; o < 256; o <<= 1) {
    int add = (t >= o) ? sh[t - o] : 0;
    __syncthreads();
    sh[t] += add;
    __syncthreads();
  }
  if (t < G) bsum[t] = sh[t] - v;  // exclusive
}

// deg may alias cursor: each element read+written only by its owning thread.
__global__ __launch_bounds__(256) void scan_write(const int* __restrict__ deg,
                                                  const int* __restrict__ bsumx,
                                                  int* __restrict__ rowptr,
                                                  int* __restrict__ cursor,
                                                  int N, int total) {
  int b = blockIdx.x, t = threadIdx.x;
  int base = b * SCHUNK + t * 8;
  int v[8], s = 0;
#pragma unroll
  for (int i = 0; i < 8; i++) {
    int g = base + i;
    v[i] = (g < N) ? deg[g] : 0;
    s += v[i];
  }
  __shared__ int sh[256];
  sh[t] = s;
  __syncthreads();
  for (int o = 1; o < 256; o <<= 1) {
    int add = (t >= o) ? sh[t - o] : 0;
    __syncthreads();
    sh[t] += add;
    __syncthreads();
  }
  int off = bsumx[b] + sh[t] - s;
#pragma unroll
  for (int i = 0; i < 8; i++) {
    int g = base + i;
    if (g < N) { rowptr[g] = off; cursor[g] = off; }
    off += v[i];
  }
  if (b == 0 && t == 0) rowptr[N] = total;
}

// scatter sorted col/val arrays directly
__global__ __launch_bounds__(256) void scatter_kernel(const int* __restrict__ idx,
                                                      const int* __restrict__ other,
                                                      const float* __restrict__ vals,
                                                      int* __restrict__ cursor,
                                                      int* __restrict__ scol,
                                                      float* __restrict__ sval, int n) {
  int e = blockIdx.x * 256 + threadIdx.x;
  if (e < n) {
    int p = atomicAdd(&cursor[idx[e]], 1);
    scol[p] = other[e];
    sval[p] = vals[e];
  }
}

// ================= spmm: wave per row, 2 half-waves x float4 =================
__global__ __launch_bounds__(256) void spmm_csr_kernel(
    const int* __restrict__ rowptr, const int* __restrict__ scol,
    const float* __restrict__ sval, const float* __restrict__ x,
    float* __restrict__ y, int N) {
  int w = (blockIdx.x * 256 + threadIdx.x) >> 6;
  if (w >= N) return;
  int lane = threadIdx.x & 63;
  int half = lane >> 5, l32 = lane & 31;
  const float4* x4 = (const float4*)x;
  int j0 = rowptr[w], j1 = rowptr[w + 1];
  float ax = 0.f, ay = 0.f, az = 0.f, aw = 0.f;
  int j = j0 + half;
  for (; j + 2 < j1; j += 4) {
    int c0 = scol[j], c1 = scol[j + 2];
    float v0 = sval[j], v1 = sval[j + 2];
    float4 x0 = x4[(size_t)c0 * 32 + l32];
    float4 x1 = x4[(size_t)c1 * 32 + l32];
    ax += v0 * x0.x + v1 * x1.x;
    ay += v0 * x0.y + v1 * x1.y;
    az += v0 * x0.z + v1 * x1.z;
    aw += v0 * x0.w + v1 * x1.w;
  }
  for (; j < j1; j += 2) {
    int c0 = scol[j];
    float v0 = sval[j];
    float4 x0 = x4[(size_t)c0 * 32 + l32];
    ax += v0 * x0.x; ay += v0 * x0.y; az += v0 * x0.z; aw += v0 * x0.w;
  }
  ax += __shfl_xor(ax, 32); ay += __shfl_xor(ay, 32);
  az += __shfl_xor(az, 32); aw += __shfl_xor(aw, 32);
  if (half == 0) {
    float4 r; r.x = ax; r.y = ay; r.z = az; r.w = aw;
    ((float4*)y)[(size_t)w * 32 + l32] = r;
  }
}

// ====== A = E^T @ X: 64-row K-tiles, plain partial writes ======
__global__ __launch_bounds__(256) void atb_kernel(
    const float* __restrict__ E, const float* __restrict__ X,
    float* __restrict__ part, int N) {
  __shared__ __align__(16) float Es[64][132];
  __shared__ __align__(16) float Xs[64][132];
  int t = threadIdx.x;
  int ip = (t >> 4) << 2;
  int jp = (t & 15) << 2;
  int rpb = (N + (int)gridDim.x - 1) / (int)gridDim.x;
  int n0 = blockIdx.x * rpb;
  int n1 = min(n0 + rpb, N);
  float acc[2][2][4][4] = {};
  const float4* E4 = (const float4*)E;
  const float4* X4 = (const float4*)X;
  for (int n = n0; n < n1; n += 64) {
    int nr = min(64, n1 - n);
    __syncthreads();
#pragma unroll
    for (int q = 0; q < 8; q++) {
      int f = t + (q << 8);
      int row = f >> 5, c4 = f & 31;
      float4 ev = {0.f, 0.f, 0.f, 0.f}, xv = {0.f, 0.f, 0.f, 0.f};
      if (row < nr) {
        size_t gi = (size_t)(n + row) * 32 + c4;
        ev = E4[gi]; xv = X4[gi];
      }
      *(float4*)&Es[row][c4 << 2] = ev;
      *(float4*)&Xs[row][c4 << 2] = xv;
    }
    __syncthreads();
#pragma unroll 2
    for (int rr = 0; rr < 64; rr++) {
      float4 e0 = *(const float4*)&Es[rr][ip];
      float4 e1 = *(const float4*)&Es[rr][ip + 64];
      float4 x0 = *(const float4*)&Xs[rr][jp];
      float4 x1 = *(const float4*)&Xs[rr][jp + 64];
      const float* e0p = (const float*)&e0;
      const float* e1p = (const float*)&e1;
      const float* x0p = (const float*)&x0;
      const float* x1p = (const float*)&x1;
#pragma unroll
      for (int ai = 0; ai < 4; ai++)
#pragma unroll
        for (int aj = 0; aj < 4; aj++) {
          acc[0][0][ai][aj] += e0p[ai] * x0p[aj];
          acc[0][1][ai][aj] += e0p[ai] * x1p[aj];
          acc[1][0][ai][aj] += e1p[ai] * x0p[aj];
          acc[1][1][ai][aj] += e1p[ai] * x1p[aj];
        }
    }
  }
  float* dst = part + (size_t)blockIdx.x * 16384;
#pragma unroll
  for (int rh = 0; rh < 2; rh++)
#pragma unroll
    for (int ai = 0; ai < 4; ai++) {
      int row = rh * 64 + ip + ai;
#pragma unroll
      for (int ch = 0; ch < 2; ch++) {
        float4 v;
        v.x = acc[rh][ch][ai][0]; v.y = acc[rh][ch][ai][1];
        v.z = acc[rh][ch][ai][2]; v.w = acc[rh][ch][ai][3];
        *(float4*)&dst[row * 128 + ch * 64 + jp] = v;
      }
    }
}

__global__ __launch_bounds__(256) void reduce_atb_kernel(
    const float* __restrict__ part, float* __restrict__ A) {
  int e4 = blockIdx.x * 256 + threadIdx.x;
  const float4* p4 = (const float4*)part;
  float4 s = {0.f, 0.f, 0.f, 0.f};
#pragma unroll 4
  for (int b = 0; b < ATBB; b++) {
    float4 v = p4[(size_t)b * 4096 + e4];
    s.x += v.x; s.y += v.y; s.z += v.z; s.w += v.w;
  }
  ((float4*)A)[e4] = s;
}

// ---------- chain: column-strip parallel, W staged in LDS ----------
__global__ __launch_bounds__(256) void chain_kernel(
    const float* __restrict__ A_u, const float* __restrict__ A_i,
    const float* __restrict__ uhy, const float* __restrict__ ihy,
    const float* __restrict__ Wu_l, const float* __restrict__ Wi_l,
    float* __restrict__ B_u, float* __restrict__ B_i) {
  __shared__ float Wb[128 * 132];
  __shared__ float LA[128][16];
  __shared__ float LB[128][16];
  int side = blockIdx.x >> 3, strip = blockIdx.x & 7;
  const float* A = side ? A_i : A_u;
  const float* hy = side ? ihy : uhy;
  const float* W = side ? Wi_l : Wu_l;
  float* Bo = side ? B_i : B_u;
  int t = threadIdx.x;
  int j0 = strip * 16;
  for (int i = t; i < 2048; i += 256) LA[i >> 4][i & 15] = A[(i >> 4) * 128 + j0 + (i & 15)];
  for (int i = t; i < 16384; i += 256) Wb[(i >> 7) * 132 + (i & 127)] = hy[i];
  __syncthreads();
  int jc = t & 15, i0 = (t >> 4) * 8;
  {
    float acc[8] = {};
    for (int k = 0; k < 128; k++) {
      float lv = LA[k][jc];
      const float* wr = &Wb[k * 132 + i0];
#pragma unroll
      for (int a = 0; a < 8; a++) acc[a] += wr[a] * lv;
    }
#pragma unroll
    for (int a = 0; a < 8; a++) LB[i0 + a][jc] = lk(acc[a]);
  }
  __syncthreads();
  float (*pin)[16] = LB;
  float (*pout)[16] = LA;
  for (int s = 0; s < 3; s++) {
    for (int i = t; i < 16384; i += 256) Wb[(i >> 7) * 132 + (i & 127)] = W[s * 16384 + i];
    __syncthreads();
    float acc[8] = {};
    for (int k = 0; k < 128; k++) {
      float lv = pin[k][jc];
      const float* wr = &Wb[k * 132 + i0];
#pragma unroll
      for (int a = 0; a < 8; a++) acc[a] += wr[a] * lv;
    }
#pragma unroll
    for (int a = 0; a < 8; a++) pout[i0 + a][jc] = lk(acc[a]) + pin[i0 + a][jc];
    __syncthreads();
    float (*tmp)[16] = pin; pin = pout; pout = tmp;
  }
  for (int i = t; i < 16384; i += 256) Wb[(i >> 7) * 132 + (i & 127)] = hy[i];
  __syncthreads();
  {
    int i = t >> 1, jb = (t & 1) * 8;
    float acc[8] = {};
    for (int k = 0; k < 128; k++) {
      float hv = Wb[i * 132 + k];
      const float* lr = &pin[k][jb];
#pragma unroll
      for (int b = 0; b < 8; b++) acc[b] += hv * lr[b];
    }
#pragma unroll
    for (int b = 0; b < 8; b++) Bo[i * 128 + j0 + jb + b] = acc[b];
  }
}

// ---------- fused: h=leaky(E@B); cur += leaky(gnn)+h ----------
// 512 thr, 128-row tile. Only B in LDS (64KB); E read via 16-lane-broadcast
// global loads (each E element fetched once per tile). 2 blocks/CU.
__global__ __launch_bounds__(512) void nmul_upd_kernel(
    const float* __restrict__ E, const float* __restrict__ Bm,
    const float* __restrict__ gnn, float* __restrict__ cur, int N) {
  __shared__ __align__(16) float Bs[128][128];
  int t = threadIdx.x;
  int dg = t & 15, rg = t >> 4;  // rg 0..31
  const float4* B4 = (const float4*)Bm;
#pragma unroll
  for (int q = 0; q < 8; q++) {
    int f = t + (q << 9);
    *(float4*)&Bs[f >> 5][(f & 31) << 2] = B4[f];
  }
  __syncthreads();
  int n0 = blockIdx.x << 7;
  const float4* E4 = (const float4*)E;
  float acc[4][8] = {};
  int rows[4];
  bool val[4];
#pragma unroll
  for (int a = 0; a < 4; a++) { rows[a] = n0 + rg + (a << 5); val[a] = rows[a] < N; }
  for (int h4 = 0; h4 < 128; h4 += 4) {
    float4 ev[4];
#pragma unroll
    for (int a = 0; a < 4; a++)
      ev[a] = val[a] ? E4[(size_t)rows[a] * 32 + (h4 >> 2)]
                     : make_float4(0.f, 0.f, 0.f, 0.f);
#pragma unroll
    for (int hh = 0; hh < 4; hh++) {
      float4 b0 = *(const float4*)&Bs[h4 + hh][dg << 2];
      float4 b1 = *(const float4*)&Bs[h4 + hh][(dg << 2) + 64];
#pragma unroll
      for (int a = 0; a < 4; a++) {
        float e = ((const float*)&ev[a])[hh];
        acc[a][0] += e * b0.x; acc[a][1] += e * b0.y;
        acc[a][2] += e * b0.z; acc[a][3] += e * b0.w;
        acc[a][4] += e * b1.x; acc[a][5] += e * b1.y;
        acc[a][6] += e * b1.z; acc[a][7] += e * b1.w;
      }
    }
  }
#pragma unroll
  for (int a = 0; a < 4; a++) {
    if (val[a]) {
      size_t base = (size_t)rows[a] * DD + (dg << 2);
      float4 g0 = *(const float4*)(gnn + base);
      float4 g1 = *(const float4*)(gnn + base + 64);
      float4 c0 = *(const float4*)(cur + base);
      float4 c1 = *(const float4*)(cur + base + 64);
      c0.x += lk(g0.x) + lk(acc[a][0]); c0.y += lk(g0.y) + lk(acc[a][1]);
      c0.z += lk(g0.z) + lk(acc[a][2]); c0.w += lk(g0.w) + lk(acc[a][3]);
      c1.x += lk(g1.x) + lk(acc[a][4]); c1.y += lk(g1.y) + lk(acc[a][5]);
      c1.z += lk(g1.z) + lk(acc[a][6]); c1.w += lk(g1.w) + lk(acc[a][7]);
      *(float4*)(cur + base) = c0; *(float4*)(cur + base + 64) = c1;
    }
  }
}

// ---------- ssl gather, batched: 32 ids/block ----------
__global__ __launch_bounds__(128) void sslgath_kernel(
    const int* __restrict__ ids, const float* __restrict__ gnn,
    const float* __restrict__ E, const float* __restrict__ Bm,
    float* __restrict__ og, float* __restrict__ oh) {
  __shared__ __align__(16) float Bs[128][132];
  __shared__ __align__(16) float Eb[32][132];
  __shared__ int idb[32];
  int t = threadIdx.x;
  int base = blockIdx.x * 32;
  if (t < 32) idb[t] = ids[base + t];
#pragma unroll
  for (int q = 0; q < 32; q++) {
    int f = t + q * 128;
    *(float4*)&Bs[f >> 5][(f & 31) << 2] = ((const float4*)Bm)[f];
  }
  __syncthreads();
#pragma unroll
  for (int q = 0; q < 8; q++) {
    int f = t + q * 128;
    int r = f >> 5, c4 = f & 31;
    *(float4*)&Eb[r][c4 << 2] = ((const float4*)E)[(size_t)idb[r] * 32 + c4];
  }
  __syncthreads();
  float acc[32] = {};
  for (int k = 0; k < 128; k++) {
    float b = Bs[k][t];
#pragma unroll
    for (int r = 0; r < 32; r++) acc[r] += Eb[r][k] * b;
  }
  for (int r = 0; r < 32; r++) {
    int id = idb[r];
    og[(size_t)(base + r) * DD + t] = lk(gnn[(size_t)id * DD + t]);
    oh[(size_t)(base + r) * DD + t] = lk(acc[r]);
  }
}

// ---------- layer-sum accumulation on gathered rows only ----------
__global__ __launch_bounds__(128) void gaccum_kernel(
    const int* __restrict__ ids, const float* __restrict__ cur,
    float* __restrict__ sumg) {
  int b = blockIdx.x, d = threadIdx.x;
  int id = ids[b];
  sumg[(size_t)b * DD + d] += cur[(size_t)id * DD + d];
}

// ---------- preds from gathered sums ----------
__global__ __launch_bounds__(256) void preds_kernel(
    const float* __restrict__ su, const float* __restrict__ si,
    float* __restrict__ outp) {
  int gid = blockIdx.x * 256 + threadIdx.x;
  int w = gid >> 6, lane = gid & 63;
  if (w >= NB) return;
  float2 a = *(const float2*)(su + (size_t)w * DD + 2 * lane);
  float2 b = *(const float2*)(si + (size_t)w * DD + 2 * lane);
  float d = a.x * b.x + a.y * b.y;
#pragma unroll
  for (int o = 32; o > 0; o >>= 1) d += __shfl_down(d, o);
  if (lane == 0) outp[w] = d;
}

// ---------- sum of squares (reg) ----------
__global__ __launch_bounds__(256) void sumsq_kernel(
    const float* __restrict__ x, int n, float* __restrict__ outp) {
  float acc = 0.f;
  for (int i = blockIdx.x * 256 + threadIdx.x; i < n; i += gridDim.x * 256) {
    float v = x[i];
    acc += v * v;
  }
#pragma unroll
  for (int o = 32; o > 0; o >>= 1) acc += __shfl_down(acc, o);
  __shared__ float s[4];
  if ((threadIdx.x & 63) == 0) s[threadIdx.x >> 6] = acc;
  __syncthreads();
  if (threadIdx.x == 0) atomicAdd(outp, s[0] + s[1] + s[2] + s[3]);
}

// ---------- row l2-normalize: gg in place, gh -> hn ----------
__global__ __launch_bounds__(128) void norm_kernel(
    const float* __restrict__ gh, float* __restrict__ gg,
    float* __restrict__ hn) {
  int r = blockIdx.x, d = threadIdx.x;
  __shared__ float red[4];
  float hv = gh[(size_t)r * DD + d];
  float gv = gg[(size_t)r * DD + d];
  float h2 = hv * hv, g2 = gv * gv;
#pragma unroll
  for (int o = 32; o > 0; o >>= 1) { h2 += __shfl_down(h2, o); g2 += __shfl_down(g2, o); }
  if ((d & 63) == 0) { red[(d >> 6) * 2] = h2; red[(d >> 6) * 2 + 1] = g2; }
  __syncthreads();
  float hnorm = sqrtf(red[0] + red[2]);
  float gnorm = sqrtf(red[1] + red[3]);
  hn[(size_t)r * DD + d] = hv / fmaxf(hnorm, 1e-12f);
  gg[(size_t)r * DD + d] = gv / fmaxf(gnorm, 1e-12f);
}

// ---------- out[4096,128] = In @ W: 32-row tiles, W in LDS, In broadcast ----------
__global__ __launch_bounds__(256) void nmul_plain_kernel(
    const float* __restrict__ In, const float* __restrict__ Wm,
    float* __restrict__ outp) {
  __shared__ __align__(16) float Bs[128][128];
  int t = threadIdx.x;
  int dg = t & 15, rg = t >> 4;  // rg 0..15
  const float4* W4 = (const float4*)Wm;
#pragma unroll
  for (int q = 0; q < 16; q++) {
    int f = t + (q << 8);
    *(float4*)&Bs[f >> 5][(f & 31) << 2] = W4[f];
  }
  __syncthreads();
  int n0 = blockIdx.x << 5;
  const float4* I4 = (const float4*)In;
  float acc[2][8] = {};
  for (int h4 = 0; h4 < 128; h4 += 4) {
    float4 ev[2];
#pragma unroll
    for (int a = 0; a < 2; a++)
      ev[a] = I4[(size_t)(n0 + rg + (a << 4)) * 32 + (h4 >> 2)];
#pragma unroll
    for (int hh = 0; hh < 4; hh++) {
      float4 b0 = *(const float4*)&Bs[h4 + hh][dg << 2];
      float4 b1 = *(const float4*)&Bs[h4 + hh][(dg << 2) + 64];
#pragma unroll
      for (int a = 0; a < 2; a++) {
        float e = ((const float*)&ev[a])[hh];
        acc[a][0] += e * b0.x; acc[a][1] += e * b0.y;
        acc[a][2] += e * b0.z; acc[a][3] += e * b0.w;
        acc[a][4] += e * b1.x; acc[a][5] += e * b1.y;
        acc[a][6] += e * b1.z; acc[a][7] += e * b1.w;
      }
    }
  }
#pragma unroll
  for (int a = 0; a < 2; a++) {
    size_t base = (size_t)(n0 + rg + (a << 4)) * DD + (dg << 2);
    float4 v0, v1;
    v0.x = acc[a][0]; v0.y = acc[a][1]; v0.z = acc[a][2]; v0.w = acc[a][3];
    v1.x = acc[a][4]; v1.y = acc[a][5]; v1.z = acc[a][6]; v1.w = acc[a][7];
    *(float4*)(outp + base) = v0;
    *(float4*)(outp + base + 64) = v1;
  }
}

// ---------- gram: neg[i] += sum_j exp(gn_i . hw_j) ----------
// 128x64 tile; H staged XOR-swizzled [64][128] (32KB -> 4 blocks/CU);
// G via 16-lane-broadcast global reads.
__global__ __launch_bounds__(256) void gram_kernel(
    const float* __restrict__ gn, const float* __restrict__ hw,
    float* __restrict__ neg) {
  __shared__ __align__(16) float Hs[64][128];
  int t = threadIdx.x;
  int rg = t >> 4, dg = t & 15;
  int i0 = blockIdx.x << 7, j0 = blockIdx.y << 6;
  float4* Hs4 = (float4*)Hs;
  const float4* hw4 = (const float4*)hw;
#pragma unroll
  for (int q = 0; q < 8; q++) {
    int f = t + (q << 8);  // 0..2047 float4
    int j = f >> 5, k4 = f & 31;
    Hs4[j * 32 + (k4 ^ ((j >> 2) & 7))] = hw4[(size_t)(j0 + j) * 32 + k4];
  }
  __syncthreads();
  const float4* G4 = (const float4*)gn;
  float acc[8][4] = {};
  for (int h4 = 0; h4 < 128; h4 += 4) {
    int k4 = h4 >> 2;
    float4 gv[8];
#pragma unroll
    for (int a = 0; a < 8; a++)
      gv[a] = G4[(size_t)(i0 + rg + (a << 4)) * 32 + k4];
    float4 bv[4];
#pragma unroll
    for (int jj = 0; jj < 4; jj++) {
      int j = (dg << 2) + jj;
      bv[jj] = *(const float4*)&Hs[j][(k4 ^ ((j >> 2) & 7)) << 2];
    }
#pragma unroll
    for (int a = 0; a < 8; a++)
#pragma unroll
      for (int jj = 0; jj < 4; jj++)
        acc[a][jj] += gv[a].x * bv[jj].x + gv[a].y * bv[jj].y +
                      gv[a].z * bv[jj].z + gv[a].w * bv[jj].w;
  }
#pragma unroll
  for (int a = 0; a < 8; a++) {
    float s = expf(acc[a][0]) + expf(acc[a][1]) + expf(acc[a][2]) + expf(acc[a][3]);
    s += __shfl_xor(s, 1);
    s += __shfl_xor(s, 2);
    s += __shfl_xor(s, 4);
    s += __shfl_xor(s, 8);
    if (dg == 0) atomicAdd(&neg[i0 + rg + (a << 4)], s);
  }
}

// ---------- ssl finalize ----------
__global__ __launch_bounds__(256) void sslfin_kernel(
    const float* __restrict__ gn, const float* __restrict__ hw,
    const float* __restrict__ neg, float* __restrict__ outp) {
  int gid = blockIdx.x * 256 + threadIdx.x;
  int w = gid >> 6, lane = gid & 63;
  if (w >= NB) return;
  float2 a = *(const float2*)(gn + (size_t)w * DD + 2 * lane);
  float2 b = *(const float2*)(hw + (size_t)w * DD + 2 * lane);
  float d = a.x * b.x + a.y * b.y;
#pragma unroll
  for (int o = 32; o > 0; o >>= 1) d += __shfl_down(d, o);
  if (lane == 0) {
    float pos = expf(d);
    float v = -logf(pos / (neg[w] + 1e-8f) + 1e-8f);
    atomicAdd(outp, v);
  }
}

extern "C" void kernel_launch(void* const* d_in, const int* in_sizes, int n_in,
                              void* d_out, int out_size, void* d_ws, size_t ws_size,
                              hipStream_t stream) {
  (void)in_sizes; (void)n_in; (void)out_size; (void)ws_size;
  const int* uids = (const int*)d_in[0];
  const int* iids = (const int*)d_in[1];
  const int* arow = (const int*)d_in[2];
  const int* acol = (const int*)d_in[3];
  const float* avals = (const float*)d_in[4];
  const float* uE = (const float*)d_in[5];
  const float* iE = (const float*)d_in[6];
  const float* uhy = (const float*)d_in[7];
  const float* ihy = (const float*)d_in[8];
  const float* Wu = (const float*)d_in[9];
  const float* Wi = (const float*)d_in[10];
  const float* Wt = (const float*)d_in[11];
  float* out = (float*)d_out;

  // workspace layout (~209 MB)
  float* p = (float*)d_ws;
  float* cur_u = p; p += (size_t)NU * DD;
  float* gnn_u = p; p += (size_t)NU * DD;
  float* cur_i = p; p += (size_t)NI * DD;
  float* gnn_i = p; p += (size_t)NI * DD;
  float* A_u = p; p += HH * DD;
  float* A_i = p; p += HH * DD;
  float* B_u = p; p += HH * DD;
  float* B_i = p; p += HH * DD;
  float* sumg_u = p; p += (size_t)NB * DD;
  float* sumg_i = p; p += (size_t)NB * DD;
  float* region = p; p += (size_t)ATBB * 16384;  // Apart ∪ {gg, gh, hn}
  float* negb = p; p += 4 * NB;
  int* rowptr_u = (int*)p; p += NU + 1;
  int* cursor_u = (int*)p; p += NU;
  int* rowptr_i = (int*)p; p += NI + 1;
  int* cursor_i = (int*)p; p += NI;
  int* bsum = (int*)p; p += 256;
  int* scol_u = (int*)p; p += NE;
  float* sval_u = p; p += NE;
  int* scol_i = (int*)p; p += NE;
  float* sval_i = p; p += NE;

  float* Apart = region;
  float* gg = region;
  float* gh = region + (size_t)NB * DD;
  float* hn = region + 2 * (size_t)NB * DD;

  const int GU = (NU + SCHUNK - 1) / SCHUNK;
  const int GI = (NI + SCHUNK - 1) / SCHUNK;
  const int EB = (NE + 255) / 256;
  const int TU = (NU + 127) >> 7;  // 782
  const int TI = (NI + 127) >> 7;  // 391

  // ---- CSR build ----
  hipMemsetAsync(cursor_u, 0, NU * sizeof(int), stream);
  hist_kernel<<<EB, 256, 0, stream>>>(arow, cursor_u, NE);
  scan_bsum<<<GU, 256, 0, stream>>>(cursor_u, bsum, NU);
  scan_top<<<1, 256, 0, stream>>>(bsum, GU);
  scan_write<<<GU, 256, 0, stream>>>(cursor_u, bsum, rowptr_u, cursor_u, NU, NE);
  scatter_kernel<<<EB, 256, 0, stream>>>(arow, acol, avals, cursor_u, scol_u, sval_u, NE);

  hipMemsetAsync(cursor_i, 0, NI * sizeof(int), stream);
  hist_kernel<<<EB, 256, 0, stream>>>(acol, cursor_i, NE);
  scan_bsum<<<GI, 256, 0, stream>>>(cursor_i, bsum, NI);
  scan_top<<<1, 256, 0, stream>>>(bsum, GI);
  scan_write<<<GI, 256, 0, stream>>>(cursor_i, bsum, rowptr_i, cursor_i, NI, NE);
  scatter_kernel<<<EB, 256, 0, stream>>>(acol, arow, avals, cursor_i, scol_i, sval_i, NE);

  hipMemcpyAsync(cur_u, uE, (size_t)NU * DD * 4, hipMemcpyDeviceToDevice, stream);
  hipMemcpyAsync(cur_i, iE, (size_t)NI * DD * 4, hipMemcpyDeviceToDevice, stream);
  hipMemsetAsync(out + NB, 0, 2 * sizeof(float), stream);
  hipMemsetAsync(negb, 0, 4 * NB * sizeof(float), stream);
  hipMemsetAsync(sumg_u, 0, 2 * (size_t)NB * DD * 4, stream);  // sumg_u + sumg_i
  gaccum_kernel<<<NB, 128, 0, stream>>>(uids, uE, sumg_u);
  gaccum_kernel<<<NB, 128, 0, stream>>>(iids, iE, sumg_i);

  for (int l = 0; l < 2; l++) {
    const float* Wt_l = Wt + (size_t)l * DD * DD;
    spmm_csr_kernel<<<NU / 4, 256, 0, stream>>>(rowptr_u, scol_u, sval_u, cur_i, gnn_u, NU);
    spmm_csr_kernel<<<NI / 4, 256, 0, stream>>>(rowptr_i, scol_i, sval_i, cur_u, gnn_i, NI);
    atb_kernel<<<ATBB, 256, 0, stream>>>(uE, cur_u, Apart, NU);
    reduce_atb_kernel<<<16, 256, 0, stream>>>(Apart, A_u);
    atb_kernel<<<ATBB, 256, 0, stream>>>(iE, cur_i, Apart, NI);
    reduce_atb_kernel<<<16, 256, 0, stream>>>(Apart, A_i);
    chain_kernel<<<16, 256, 0, stream>>>(A_u, A_i, uhy, ihy,
        Wu + (size_t)l * 3 * HH * HH, Wi + (size_t)l * 3 * HH * HH, B_u, B_i);

    // ---- user side ----
    sslgath_kernel<<<NB / 32, 128, 0, stream>>>(uids, gnn_u, uE, B_u, gg, gh);
    nmul_upd_kernel<<<TU, 512, 0, stream>>>(uE, B_u, gnn_u, cur_u, NU);
    gaccum_kernel<<<NB, 128, 0, stream>>>(uids, cur_u, sumg_u);
    norm_kernel<<<NB, 128, 0, stream>>>(gh, gg, hn);
    nmul_plain_kernel<<<NB / 32, 256, 0, stream>>>(hn, Wt_l, gh);
    gram_kernel<<<dim3(NB / 128, NB / 64), 256, 0, stream>>>(gg, gh, negb + (2 * l) * NB);
    sslfin_kernel<<<NB / 4, 256, 0, stream>>>(gg, gh, negb + (2 * l) * NB, out + NB);

    // ---- item side ----
    sslgath_kernel<<<NB / 32, 128, 0, stream>>>(iids, gnn_i, iE, B_i, gg, gh);
    nmul_upd_kernel<<<TI, 512, 0, stream>>>(iE, B_i, gnn_i, cur_i, NI);
    gaccum_kernel<<<NB, 128, 0, stream>>>(iids, cur_i, sumg_i);
    norm_kernel<<<NB, 128, 0, stream>>>(gh, gg, hn);
    nmul_plain_kernel<<<NB / 32, 256, 0, stream>>>(hn, Wt_l, gh);
    gram_kernel<<<dim3(NB / 128, NB / 64), 256, 0, stream>>>(gg, gh, negb + (2 * l + 1) * NB);
    sslfin_kernel<<<NB / 4, 256, 0, stream>>>(gg, gh, negb + (2 * l + 1) * NB, out + NB);
  }

  preds_kernel<<<NB / 4, 256, 0, stream>>>(sumg_u, sumg_i, out);
  sumsq_kernel<<<2048, 256, 0, stream>>>(uE, NU * DD, out + NB + 1);
  sumsq_kernel<<<1024, 256, 0, stream>>>(iE, NI * DD, out + NB + 1);
  sumsq_kernel<<<64, 256, 0, stream>>>(uhy, DD * HH, out + NB + 1);
  sumsq_kernel<<<64, 256, 0, stream>>>(ihy, DD * HH, out + NB + 1);
}

// Round 11
// 2102.182 us; speedup vs baseline: 3.2231x; 1.0547x over previous
//
#include <hip/hip_runtime.h>

#define NU 100000
#define NI 50000
#define DD 128
#define HH 128
#define NE 1000000
#define NB 4096
#define SCHUNK 2048

__device__ __forceinline__ float lk(float x) { return fmaxf(0.5f * x, x); }

// ================= CSR build =================
__global__ __launch_bounds__(256) void hist_kernel(const int* __restrict__ idx,
                                                   int* __restrict__ deg, int n) {
  int e = blockIdx.x * 256 + threadIdx.x;
  if (e < n) atomicAdd(&deg[idx[e]], 1);
}

__global__ __launch_bounds__(256) void scan_bsum(const int* __restrict__ deg,
                                                 int* __restrict__ bsum, int N) {
  int b = blockIdx.x, t = threadIdx.x;
  int base = b * SCHUNK;
  int s = 0;
  for (int i = t; i < SCHUNK; i += 256) {
    int g = base + i;
    if (g < N) s += deg[g];
  }
#pragma unroll
  for (int o = 32; o > 0; o >>= 1) s += __shfl_down(s, o);
  __shared__ int ws[4];
  if ((t & 63) == 0) ws[t >> 6] = s;
  __syncthreads();
  if (t == 0) bsum[b] = ws[0] + ws[1] + ws[2] + ws[3];
}

__global__ __launch_bounds__(256) void scan_top(int* __restrict__ bsum, int G) {
  int t = threadIdx.x;
  __shared__ int sh[256];
  int v = (t < G) ? bsum[t] : 0;
  sh[t] = v;
  __syncthreads();
  for (int o = 1; o < 256; o <<= 1) {
    int add = (t >= o) ? sh[t - o] : 0;
    __syncthreads();
    sh[t] += add;
    __syncthreads();
  }
  if (t < G) bsum[t] = sh[t] - v;  // exclusive
}

__global__ __launch_bounds__(256) void scan_write(const int* __restrict__ deg,
                                                  const int* __restrict__ bsumx,
                                                  int* __restrict__ rowptr,
                                                  int* __restrict__ cursor,
                                                  int N, int total) {
  int b = blockIdx.x, t = threadIdx.x;
  int base = b * SCHUNK + t * 8;
  int v[8], s = 0;
#pragma unroll
  for (int i = 0; i < 8; i++) {
    int g = base + i;
    v[i] = (g < N) ? deg[g] : 0;
    s += v[i];
  }
  __shared__ int sh[256];
  sh[t] = s;
  __syncthreads();
  for (int o = 1; o < 256; o <<= 1) {
    int add = (t >= o) ? sh[t - o] : 0;
    __syncthreads();
    sh[t] += add;
    __syncthreads();
  }
  int off = bsumx[b] + sh[t] - s;
#pragma unroll
  for (int i = 0; i < 8; i++) {
    int g = base + i;
    if (g < N) { rowptr[g] = off; cursor[g] = off; }
    off += v[i];
  }
  if (b == 0 && t == 0) rowptr[N] = total;
}

__global__ __launch_bounds__(256) void scatter_kernel(const int* __restrict__ idx,
                                                      const int* __restrict__ other,
                                                      const float* __restrict__ vals,
                                                      int* __restrict__ cursor,
                                                      int* __restrict__ scol,
                                                      float* __restrict__ sval, int n) {
  int e = blockIdx.x * 256 + threadIdx.x;
  if (e < n) {
    int p = atomicAdd(&cursor[idx[e]], 1);
    scol[p] = other[e];
    sval[p] = vals[e];
  }
}

// ================= spmm both sides: wave per row =================
__global__ __launch_bounds__(256) void spmm_both_kernel(
    const int* __restrict__ rp_u, const int* __restrict__ sc_u,
    const float* __restrict__ sv_u, const float* __restrict__ xu,
    float* __restrict__ yu,
    const int* __restrict__ rp_i, const int* __restrict__ sc_i,
    const float* __restrict__ sv_i, const float* __restrict__ xi,
    float* __restrict__ yi) {
  int bid = blockIdx.x;
  const int* rowptr; const int* scol; const float* sval;
  const float* x; float* y; int N;
  if (bid < NU / 4) {
    rowptr = rp_u; scol = sc_u; sval = sv_u; x = xu; y = yu; N = NU;
  } else {
    bid -= NU / 4;
    rowptr = rp_i; scol = sc_i; sval = sv_i; x = xi; y = yi; N = NI;
  }
  int w = bid * 4 + (threadIdx.x >> 6);
  if (w >= N) return;
  int lane = threadIdx.x & 63;
  int half = lane >> 5, l32 = lane & 31;
  const float4* x4 = (const float4*)x;
  int j0 = rowptr[w], j1 = rowptr[w + 1];
  float ax = 0.f, ay = 0.f, az = 0.f, aw = 0.f;
  int j = j0 + half;
  for (; j + 2 < j1; j += 4) {
    int c0 = scol[j], c1 = scol[j + 2];
    float v0 = sval[j], v1 = sval[j + 2];
    float4 x0 = x4[(size_t)c0 * 32 + l32];
    float4 x1 = x4[(size_t)c1 * 32 + l32];
    ax += v0 * x0.x + v1 * x1.x;
    ay += v0 * x0.y + v1 * x1.y;
    az += v0 * x0.z + v1 * x1.z;
    aw += v0 * x0.w + v1 * x1.w;
  }
  for (; j < j1; j += 2) {
    int c0 = scol[j];
    float v0 = sval[j];
    float4 x0 = x4[(size_t)c0 * 32 + l32];
    ax += v0 * x0.x; ay += v0 * x0.y; az += v0 * x0.z; aw += v0 * x0.w;
  }
  ax += __shfl_xor(ax, 32); ay += __shfl_xor(ay, 32);
  az += __shfl_xor(az, 32); aw += __shfl_xor(aw, 32);
  if (half == 0) {
    float4 r; r.x = ax; r.y = ay; r.z = az; r.w = aw;
    ((float4*)y)[(size_t)w * 32 + l32] = r;
  }
}

// ====== A0 = E^T @ E (both sides, 256 partial blocks each) ======
__global__ __launch_bounds__(256) void atb0_kernel(
    const float* __restrict__ uE, const float* __restrict__ iE,
    float* __restrict__ part) {
  int side = blockIdx.x >> 8, bid = blockIdx.x & 255;
  const float* E = side ? iE : uE;
  int N = side ? NI : NU;
  __shared__ __align__(16) float Es[64][132];
  int t = threadIdx.x;
  int ip = (t >> 4) << 2, jp = (t & 15) << 2;
  int rpb = (N + 255) >> 8;
  int n0 = bid * rpb;
  int n1 = min(n0 + rpb, N);
  float acc[2][2][4][4] = {};
  const float4* E4 = (const float4*)E;
  for (int n = n0; n < n1; n += 64) {
    int nr = min(64, n1 - n);
    __syncthreads();
#pragma unroll
    for (int q = 0; q < 8; q++) {
      int f = t + (q << 8);
      int row = f >> 5, c4 = f & 31;
      float4 ev = {0.f, 0.f, 0.f, 0.f};
      if (row < nr) ev = E4[(size_t)(n + row) * 32 + c4];
      *(float4*)&Es[row][c4 << 2] = ev;
    }
    __syncthreads();
#pragma unroll 2
    for (int rr = 0; rr < 64; rr++) {
      float4 e0 = *(const float4*)&Es[rr][ip];
      float4 e1 = *(const float4*)&Es[rr][ip + 64];
      float4 x0 = *(const float4*)&Es[rr][jp];
      float4 x1 = *(const float4*)&Es[rr][jp + 64];
      const float* e0p = (const float*)&e0;
      const float* e1p = (const float*)&e1;
      const float* x0p = (const float*)&x0;
      const float* x1p = (const float*)&x1;
#pragma unroll
      for (int ai = 0; ai < 4; ai++)
#pragma unroll
        for (int aj = 0; aj < 4; aj++) {
          acc[0][0][ai][aj] += e0p[ai] * x0p[aj];
          acc[0][1][ai][aj] += e0p[ai] * x1p[aj];
          acc[1][0][ai][aj] += e1p[ai] * x0p[aj];
          acc[1][1][ai][aj] += e1p[ai] * x1p[aj];
        }
    }
  }
  float* dst = part + (size_t)blockIdx.x * 16384;
#pragma unroll
  for (int rh = 0; rh < 2; rh++)
#pragma unroll
    for (int ai = 0; ai < 4; ai++) {
      int row = rh * 64 + ip + ai;
#pragma unroll
      for (int ch = 0; ch < 2; ch++) {
        float4 v;
        v.x = acc[rh][ch][ai][0]; v.y = acc[rh][ch][ai][1];
        v.z = acc[rh][ch][ai][2]; v.w = acc[rh][ch][ai][3];
        *(float4*)&dst[row * 128 + ch * 64 + jp] = v;
      }
    }
}

// ---------- reduce 256 partials per side into A_u / A_i ----------
__global__ __launch_bounds__(256) void reduce_both_kernel(
    const float* __restrict__ part, float* __restrict__ A_u,
    float* __restrict__ A_i) {
  int b = blockIdx.x;          // 0..31
  int side = b >> 4;
  int e4 = (b & 15) * 256 + threadIdx.x;  // 0..4095 float4
  const float4* p4 = (const float4*)(part + (size_t)side * 256 * 16384);
  float4 s = {0.f, 0.f, 0.f, 0.f};
#pragma unroll 4
  for (int k = 0; k < 256; k++) {
    float4 v = p4[(size_t)k * 4096 + e4];
    s.x += v.x; s.y += v.y; s.z += v.z; s.w += v.w;
  }
  ((float4*)(side ? A_i : A_u))[e4] = s;
}

// ---------- chain: column-strip parallel, W staged in LDS ----------
__global__ __launch_bounds__(256) void chain_kernel(
    const float* __restrict__ A_u, const float* __restrict__ A_i,
    const float* __restrict__ uhy, const float* __restrict__ ihy,
    const float* __restrict__ Wu_l, const float* __restrict__ Wi_l,
    float* __restrict__ B_u, float* __restrict__ B_i) {
  __shared__ float Wb[128 * 132];
  __shared__ float LA[128][16];
  __shared__ float LB[128][16];
  int side = blockIdx.x >> 3, strip = blockIdx.x & 7;
  const float* A = side ? A_i : A_u;
  const float* hy = side ? ihy : uhy;
  const float* W = side ? Wi_l : Wu_l;
  float* Bo = side ? B_i : B_u;
  int t = threadIdx.x;
  int j0 = strip * 16;
  for (int i = t; i < 2048; i += 256) LA[i >> 4][i & 15] = A[(i >> 4) * 128 + j0 + (i & 15)];
  for (int i = t; i < 16384; i += 256) Wb[(i >> 7) * 132 + (i & 127)] = hy[i];
  __syncthreads();
  int jc = t & 15, i0 = (t >> 4) * 8;
  {
    float acc[8] = {};
    for (int k = 0; k < 128; k++) {
      float lv = LA[k][jc];
      const float* wr = &Wb[k * 132 + i0];
#pragma unroll
      for (int a = 0; a < 8; a++) acc[a] += wr[a] * lv;
    }
#pragma unroll
    for (int a = 0; a < 8; a++) LB[i0 + a][jc] = lk(acc[a]);
  }
  __syncthreads();
  float (*pin)[16] = LB;
  float (*pout)[16] = LA;
  for (int s = 0; s < 3; s++) {
    for (int i = t; i < 16384; i += 256) Wb[(i >> 7) * 132 + (i & 127)] = W[s * 16384 + i];
    __syncthreads();
    float acc[8] = {};
    for (int k = 0; k < 128; k++) {
      float lv = pin[k][jc];
      const float* wr = &Wb[k * 132 + i0];
#pragma unroll
      for (int a = 0; a < 8; a++) acc[a] += wr[a] * lv;
    }
#pragma unroll
    for (int a = 0; a < 8; a++) pout[i0 + a][jc] = lk(acc[a]) + pin[i0 + a][jc];
    __syncthreads();
    float (*tmp)[16] = pin; pin = pout; pout = tmp;
  }
  for (int i = t; i < 16384; i += 256) Wb[(i >> 7) * 132 + (i & 127)] = hy[i];
  __syncthreads();
  {
    int i = t >> 1, jb = (t & 1) * 8;
    float acc[8] = {};
    for (int k = 0; k < 128; k++) {
      float hv = Wb[i * 132 + k];
      const float* lr = &pin[k][jb];
#pragma unroll
      for (int b = 0; b < 8; b++) acc[b] += hv * lr[b];
    }
#pragma unroll
    for (int b = 0; b < 8; b++) Bo[i * 128 + j0 + jb + b] = acc[b];
  }
}

// ====== fused: h=leaky(E@B); cur += leaky(gnn)+h; [+ atb partial for next layer] ======
// grid 512 (256/side), 512 thr. B in LDS (64KB). atb pass re-reads L2-hot E/cur.
template <int DOATB>
__global__ __launch_bounds__(512) void nmul_atb_kernel(
    const float* __restrict__ uE, const float* __restrict__ Bu,
    const float* __restrict__ gu, float* __restrict__ cu,
    const float* __restrict__ iE, const float* __restrict__ Bi,
    const float* __restrict__ gi, float* __restrict__ ci,
    float* __restrict__ part) {
  int side = blockIdx.x >> 8, bid = blockIdx.x & 255;
  const float* E = side ? iE : uE;
  const float* Bm = side ? Bi : Bu;
  const float* gnn = side ? gi : gu;
  float* cur = side ? ci : cu;
  int N = side ? NI : NU;
  int ntiles = (N + 127) >> 7;
  __shared__ __align__(16) float Bs[128][128];
  int t = threadIdx.x;
  int dg = t & 15, rg = t >> 4;  // rg 0..31
  const float4* B4 = (const float4*)Bm;
#pragma unroll
  for (int q = 0; q < 8; q++) {
    int f = t + (q << 9);
    *(float4*)&Bs[f >> 5][(f & 31) << 2] = B4[f];
  }
  __syncthreads();
  float atb[4][8] = {};
  const float4* E4 = (const float4*)E;
  const float4* C4 = (const float4*)cur;
  for (int tile = bid; tile < ntiles; tile += 256) {
    int n0 = tile << 7;
    float acc[4][8] = {};
    int rows[4];
    bool val[4];
#pragma unroll
    for (int a = 0; a < 4; a++) { rows[a] = n0 + rg + (a << 5); val[a] = rows[a] < N; }
    for (int h4 = 0; h4 < 128; h4 += 4) {
      float4 ev[4];
#pragma unroll
      for (int a = 0; a < 4; a++)
        ev[a] = val[a] ? E4[(size_t)rows[a] * 32 + (h4 >> 2)]
                       : make_float4(0.f, 0.f, 0.f, 0.f);
#pragma unroll
      for (int hh = 0; hh < 4; hh++) {
        float4 b0 = *(const float4*)&Bs[h4 + hh][dg << 2];
        float4 b1 = *(const float4*)&Bs[h4 + hh][(dg << 2) + 64];
#pragma unroll
        for (int a = 0; a < 4; a++) {
          float e = ((const float*)&ev[a])[hh];
          acc[a][0] += e * b0.x; acc[a][1] += e * b0.y;
          acc[a][2] += e * b0.z; acc[a][3] += e * b0.w;
          acc[a][4] += e * b1.x; acc[a][5] += e * b1.y;
          acc[a][6] += e * b1.z; acc[a][7] += e * b1.w;
        }
      }
    }
#pragma unroll
    for (int a = 0; a < 4; a++) {
      if (val[a]) {
        size_t base = (size_t)rows[a] * DD + (dg << 2);
        float4 g0 = *(const float4*)(gnn + base);
        float4 g1 = *(const float4*)(gnn + base + 64);
        float4 c0 = *(const float4*)(cur + base);
        float4 c1 = *(const float4*)(cur + base + 64);
        c0.x += lk(g0.x) + lk(acc[a][0]); c0.y += lk(g0.y) + lk(acc[a][1]);
        c0.z += lk(g0.z) + lk(acc[a][2]); c0.w += lk(g0.w) + lk(acc[a][3]);
        c1.x += lk(g1.x) + lk(acc[a][4]); c1.y += lk(g1.y) + lk(acc[a][5]);
        c1.z += lk(g1.z) + lk(acc[a][6]); c1.w += lk(g1.w) + lk(acc[a][7]);
        *(float4*)(cur + base) = c0; *(float4*)(cur + base + 64) = c1;
      }
    }
    if (DOATB) {
      __syncthreads();  // tile's cur writes visible block-wide
      int nr = min(128, N - n0);
      for (int rr = 0; rr < nr; rr++) {
        size_t rb = (size_t)(n0 + rr) * 32;
        float4 ev = E4[rb + rg];             // k = rg*4+{0..3}
        float4 c0 = C4[rb + (dg << 1)];      // j = dg*8+{0..3}
        float4 c1 = C4[rb + (dg << 1) + 1];  // j = dg*8+{4..7}
        const float* ep = (const float*)&ev;
#pragma unroll
        for (int ai = 0; ai < 4; ai++) {
          float e = ep[ai];
          atb[ai][0] += e * c0.x; atb[ai][1] += e * c0.y;
          atb[ai][2] += e * c0.z; atb[ai][3] += e * c0.w;
          atb[ai][4] += e * c1.x; atb[ai][5] += e * c1.y;
          atb[ai][6] += e * c1.z; atb[ai][7] += e * c1.w;
        }
      }
    }
  }
  if (DOATB) {
    float* dst = part + (size_t)blockIdx.x * 16384;
#pragma unroll
    for (int ai = 0; ai < 4; ai++) {
      int k = (rg << 2) + ai;
      float4 v0, v1;
      v0.x = atb[ai][0]; v0.y = atb[ai][1]; v0.z = atb[ai][2]; v0.w = atb[ai][3];
      v1.x = atb[ai][4]; v1.y = atb[ai][5]; v1.z = atb[ai][6]; v1.w = atb[ai][7];
      *(float4*)&dst[k * 128 + (dg << 3)] = v0;
      *(float4*)&dst[k * 128 + (dg << 3) + 4] = v1;
    }
  }
}

// ---------- ssl gather, both sides, 32 ids/block ----------
__global__ __launch_bounds__(128) void sslgath_both_kernel(
    const int* __restrict__ uids, const int* __restrict__ iids,
    const float* __restrict__ gu, const float* __restrict__ gi,
    const float* __restrict__ uE, const float* __restrict__ iE,
    const float* __restrict__ Bu, const float* __restrict__ Bi,
    float* __restrict__ ggu, float* __restrict__ ghu,
    float* __restrict__ ggi, float* __restrict__ ghi) {
  int side = blockIdx.y;
  const int* ids = side ? iids : uids;
  const float* gnn = side ? gi : gu;
  const float* E = side ? iE : uE;
  const float* Bm = side ? Bi : Bu;
  float* og = side ? ggi : ggu;
  float* oh = side ? ghi : ghu;
  __shared__ __align__(16) float Bs[128][132];
  __shared__ __align__(16) float Eb[32][132];
  __shared__ int idb[32];
  int t = threadIdx.x;
  int base = blockIdx.x * 32;
  if (t < 32) idb[t] = ids[base + t];
#pragma unroll
  for (int q = 0; q < 32; q++) {
    int f = t + q * 128;
    *(float4*)&Bs[f >> 5][(f & 31) << 2] = ((const float4*)Bm)[f];
  }
  __syncthreads();
#pragma unroll
  for (int q = 0; q < 8; q++) {
    int f = t + q * 128;
    int r = f >> 5, c4 = f & 31;
    *(float4*)&Eb[r][c4 << 2] = ((const float4*)E)[(size_t)idb[r] * 32 + c4];
  }
  __syncthreads();
  float acc[32] = {};
  for (int k = 0; k < 128; k++) {
    float b = Bs[k][t];
#pragma unroll
    for (int r = 0; r < 32; r++) acc[r] += Eb[r][k] * b;
  }
  for (int r = 0; r < 32; r++) {
    int id = idb[r];
    og[(size_t)(base + r) * DD + t] = lk(gnn[(size_t)id * DD + t]);
    oh[(size_t)(base + r) * DD + t] = lk(acc[r]);
  }
}

// ---------- layer-sum accumulation on gathered rows, both sides ----------
__global__ __launch_bounds__(128) void gaccum_both_kernel(
    const int* __restrict__ uids, const int* __restrict__ iids,
    const float* __restrict__ cu, const float* __restrict__ ci,
    float* __restrict__ su, float* __restrict__ si) {
  int side = blockIdx.y;
  const int* ids = side ? iids : uids;
  const float* cur = side ? ci : cu;
  float* sumg = side ? si : su;
  int b = blockIdx.x, d = threadIdx.x;
  int id = ids[b];
  sumg[(size_t)b * DD + d] += cur[(size_t)id * DD + d];
}

// ---------- preds from gathered sums ----------
__global__ __launch_bounds__(256) void preds_kernel(
    const float* __restrict__ su, const float* __restrict__ si,
    float* __restrict__ outp) {
  int gid = blockIdx.x * 256 + threadIdx.x;
  int w = gid >> 6, lane = gid & 63;
  if (w >= NB) return;
  float2 a = *(const float2*)(su + (size_t)w * DD + 2 * lane);
  float2 b = *(const float2*)(si + (size_t)w * DD + 2 * lane);
  float d = a.x * b.x + a.y * b.y;
#pragma unroll
  for (int o = 32; o > 0; o >>= 1) d += __shfl_down(d, o);
  if (lane == 0) outp[w] = d;
}

// ---------- all 4 sum-of-squares in one launch ----------
__global__ __launch_bounds__(256) void sumsq4_kernel(
    const float* __restrict__ uE, const float* __restrict__ iE,
    const float* __restrict__ uhy, const float* __restrict__ ihy,
    float* __restrict__ outp) {
  int b = blockIdx.x;
  const float* x; int n, base, nb;
  if (b < 2048) { x = uE; n = NU * DD; base = b; nb = 2048; }
  else if (b < 3072) { x = iE; n = NI * DD; base = b - 2048; nb = 1024; }
  else if (b < 3136) { x = uhy; n = DD * HH; base = b - 3072; nb = 64; }
  else { x = ihy; n = DD * HH; base = b - 3136; nb = 64; }
  float acc = 0.f;
  for (int i = base * 256 + threadIdx.x; i < n; i += nb * 256) {
    float v = x[i];
    acc += v * v;
  }
#pragma unroll
  for (int o = 32; o > 0; o >>= 1) acc += __shfl_down(acc, o);
  __shared__ float s[4];
  if ((threadIdx.x & 63) == 0) s[threadIdx.x >> 6] = acc;
  __syncthreads();
  if (threadIdx.x == 0) atomicAdd(outp, s[0] + s[1] + s[2] + s[3]);
}

// ---------- fused l2norm + (hn @ Wt), both sides; gg normalized in place ----------
// grid 256 (128 blocks/side), 256 thr; per block one 32-row tile.
__global__ __launch_bounds__(256) void normplain_kernel(
    float* __restrict__ ggu, float* __restrict__ ghu,
    float* __restrict__ ggi, float* __restrict__ ghi,
    const float* __restrict__ Wt_l) {
  int side = blockIdx.x >> 7, bid = blockIdx.x & 127;
  float* gg = side ? ggi : ggu;
  float* gh = side ? ghi : ghu;
  __shared__ __align__(16) float Ws[128][128];
  __shared__ __align__(16) float Gh[32][132];
  __shared__ __align__(16) float Gg[32][132];
  __shared__ float red[32][8][2];
  __shared__ float inv[32][2];
  int t = threadIdx.x;
  const float4* W4 = (const float4*)Wt_l;
#pragma unroll
  for (int q = 0; q < 16; q++) {
    int f = t + (q << 8);
    *(float4*)&Ws[f >> 5][(f & 31) << 2] = W4[f];
  }
  int n0 = bid << 5;
  const float4* gh4 = (const float4*)gh;
  const float4* gg4 = (const float4*)gg;
#pragma unroll
  for (int q = 0; q < 4; q++) {
    int f = t + (q << 8);  // 0..1023
    int r = f >> 5, c4 = f & 31;
    *(float4*)&Gh[r][c4 << 2] = gh4[(size_t)(n0 + r) * 32 + c4];
    *(float4*)&Gg[r][c4 << 2] = gg4[(size_t)(n0 + r) * 32 + c4];
  }
  __syncthreads();
  {
    int r = t >> 3, seg = t & 7;
    float sh = 0.f, sg = 0.f;
    int k0 = seg << 4;
#pragma unroll
    for (int k = 0; k < 16; k++) {
      float a = Gh[r][k0 + k]; sh += a * a;
      float b = Gg[r][k0 + k]; sg += b * b;
    }
    red[r][seg][0] = sh; red[r][seg][1] = sg;
  }
  __syncthreads();
  if (t < 64) {
    int r = t >> 1, which = t & 1;
    float s = 0.f;
#pragma unroll
    for (int seg = 0; seg < 8; seg++) s += red[r][seg][which];
    inv[r][which] = 1.f / fmaxf(sqrtf(s), 1e-12f);
  }
  __syncthreads();
  // normalized gg write-back
  float4* ggw = (float4*)gg;
#pragma unroll
  for (int q = 0; q < 4; q++) {
    int f = t + (q << 8);
    int r = f >> 5, c4 = f & 31;
    float4 v = *(const float4*)&Gg[r][c4 << 2];
    float iv = inv[r][1];
    v.x *= iv; v.y *= iv; v.z *= iv; v.w *= iv;
    ggw[(size_t)(n0 + r) * 32 + c4] = v;
  }
  // gh = (Gh * inv_h) @ W
  int rg = t >> 4, dg = t & 15;
  float acc[2][8] = {};
  for (int k = 0; k < 128; k++) {
    float e0 = Gh[rg][k];
    float e1 = Gh[rg + 16][k];
    float4 b0 = *(const float4*)&Ws[k][dg << 2];
    float4 b1 = *(const float4*)&Ws[k][(dg << 2) + 64];
    acc[0][0] += e0 * b0.x; acc[0][1] += e0 * b0.y;
    acc[0][2] += e0 * b0.z; acc[0][3] += e0 * b0.w;
    acc[0][4] += e0 * b1.x; acc[0][5] += e0 * b1.y;
    acc[0][6] += e0 * b1.z; acc[0][7] += e0 * b1.w;
    acc[1][0] += e1 * b0.x; acc[1][1] += e1 * b0.y;
    acc[1][2] += e1 * b0.z; acc[1][3] += e1 * b0.w;
    acc[1][4] += e1 * b1.x; acc[1][5] += e1 * b1.y;
    acc[1][6] += e1 * b1.z; acc[1][7] += e1 * b1.w;
  }
#pragma unroll
  for (int a = 0; a < 2; a++) {
    int r = rg + (a << 4);
    float iv = inv[r][0];
    size_t base = (size_t)(n0 + r) * DD + (dg << 2);
    float4 v0, v1;
    v0.x = acc[a][0] * iv; v0.y = acc[a][1] * iv;
    v0.z = acc[a][2] * iv; v0.w = acc[a][3] * iv;
    v1.x = acc[a][4] * iv; v1.y = acc[a][5] * iv;
    v1.z = acc[a][6] * iv; v1.w = acc[a][7] * iv;
    *(float4*)(gh + base) = v0;
    *(float4*)(gh + base + 64) = v1;
  }
}

// ---------- gram both sides: neg[i] += sum_j exp(gn_i . hw_j) ----------
__global__ __launch_bounds__(256) void gram_both_kernel(
    const float* __restrict__ ggu, const float* __restrict__ ghu,
    const float* __restrict__ ggi, const float* __restrict__ ghi,
    float* __restrict__ negl) {
  int side = blockIdx.z;
  const float* gn = side ? ggi : ggu;
  const float* hw = side ? ghi : ghu;
  float* neg = negl + side * NB;
  __shared__ __align__(16) float Hs[64][128];
  int t = threadIdx.x;
  int rg = t >> 4, dg = t & 15;
  int i0 = blockIdx.x << 7, j0 = blockIdx.y << 6;
  float4* Hs4 = (float4*)Hs;
  const float4* hw4 = (const float4*)hw;
#pragma unroll
  for (int q = 0; q < 8; q++) {
    int f = t + (q << 8);
    int j = f >> 5, k4 = f & 31;
    Hs4[j * 32 + (k4 ^ ((j >> 2) & 7))] = hw4[(size_t)(j0 + j) * 32 + k4];
  }
  __syncthreads();
  const float4* G4 = (const float4*)gn;
  float acc[8][4] = {};
  for (int h4 = 0; h4 < 128; h4 += 4) {
    int k4 = h4 >> 2;
    float4 gv[8];
#pragma unroll
    for (int a = 0; a < 8; a++)
      gv[a] = G4[(size_t)(i0 + rg + (a << 4)) * 32 + k4];
    float4 bv[4];
#pragma unroll
    for (int jj = 0; jj < 4; jj++) {
      int j = (dg << 2) + jj;
      bv[jj] = *(const float4*)&Hs[j][(k4 ^ ((j >> 2) & 7)) << 2];
    }
#pragma unroll
    for (int a = 0; a < 8; a++)
#pragma unroll
      for (int jj = 0; jj < 4; jj++)
        acc[a][jj] += gv[a].x * bv[jj].x + gv[a].y * bv[jj].y +
                      gv[a].z * bv[jj].z + gv[a].w * bv[jj].w;
  }
#pragma unroll
  for (int a = 0; a < 8; a++) {
    float s = expf(acc[a][0]) + expf(acc[a][1]) + expf(acc[a][2]) + expf(acc[a][3]);
    s += __shfl_xor(s, 1);
    s += __shfl_xor(s, 2);
    s += __shfl_xor(s, 4);
    s += __shfl_xor(s, 8);
    if (dg == 0) atomicAdd(&neg[i0 + rg + (a << 4)], s);
  }
}

// ---------- ssl finalize, both sides ----------
__global__ __launch_bounds__(256) void sslfin_both_kernel(
    const float* __restrict__ ggu, const float* __restrict__ ghu,
    const float* __restrict__ ggi, const float* __restrict__ ghi,
    const float* __restrict__ negl, float* __restrict__ outp) {
  int side = blockIdx.y;
  const float* gn = side ? ggi : ggu;
  const float* hw = side ? ghi : ghu;
  const float* neg = negl + side * NB;
  int gid = blockIdx.x * 256 + threadIdx.x;
  int w = gid >> 6, lane = gid & 63;
  if (w >= NB) return;
  float2 a = *(const float2*)(gn + (size_t)w * DD + 2 * lane);
  float2 b = *(const float2*)(hw + (size_t)w * DD + 2 * lane);
  float d = a.x * b.x + a.y * b.y;
#pragma unroll
  for (int o = 32; o > 0; o >>= 1) d += __shfl_down(d, o);
  if (lane == 0) {
    float pos = expf(d);
    float v = -logf(pos / (neg[w] + 1e-8f) + 1e-8f);
    atomicAdd(outp, v);
  }
}

extern "C" void kernel_launch(void* const* d_in, const int* in_sizes, int n_in,
                              void* d_out, int out_size, void* d_ws, size_t ws_size,
                              hipStream_t stream) {
  (void)in_sizes; (void)n_in; (void)out_size; (void)ws_size;
  const int* uids = (const int*)d_in[0];
  const int* iids = (const int*)d_in[1];
  const int* arow = (const int*)d_in[2];
  const int* acol = (const int*)d_in[3];
  const float* avals = (const float*)d_in[4];
  const float* uE = (const float*)d_in[5];
  const float* iE = (const float*)d_in[6];
  const float* uhy = (const float*)d_in[7];
  const float* ihy = (const float*)d_in[8];
  const float* Wu = (const float*)d_in[9];
  const float* Wi = (const float*)d_in[10];
  const float* Wt = (const float*)d_in[11];
  float* out = (float*)d_out;

  // workspace layout (~217 MB)
  float* p = (float*)d_ws;
  float* cur_u = p; p += (size_t)NU * DD;
  float* gnn_u = p; p += (size_t)NU * DD;
  float* cur_i = p; p += (size_t)NI * DD;
  float* gnn_i = p; p += (size_t)NI * DD;
  float* A_u = p; p += HH * DD;
  float* A_i = p; p += HH * DD;
  float* B_u = p; p += HH * DD;
  float* B_i = p; p += HH * DD;
  float* sumg_u = p; p += (size_t)NB * DD;
  float* sumg_i = p; p += (size_t)NB * DD;
  float* Apart = p; p += (size_t)512 * 16384;  // 32 MB: 256 partials/side
  float* ggu = p; p += (size_t)NB * DD;
  float* ghu = p; p += (size_t)NB * DD;
  float* ggi = p; p += (size_t)NB * DD;
  float* ghi = p; p += (size_t)NB * DD;
  float* negb = p; p += 4 * NB;
  int* rowptr_u = (int*)p; p += NU + 1;
  int* cursor_u = (int*)p; p += NU;
  int* rowptr_i = (int*)p; p += NI + 1;
  int* cursor_i = (int*)p; p += NI;
  int* bsum = (int*)p; p += 256;
  int* scol_u = (int*)p; p += NE;
  float* sval_u = p; p += NE;
  int* scol_i = (int*)p; p += NE;
  float* sval_i = p; p += NE;

  const int GU = (NU + SCHUNK - 1) / SCHUNK;
  const int GI = (NI + SCHUNK - 1) / SCHUNK;
  const int EB = (NE + 255) / 256;

  // ---- CSR build ----
  hipMemsetAsync(cursor_u, 0, NU * sizeof(int), stream);
  hist_kernel<<<EB, 256, 0, stream>>>(arow, cursor_u, NE);
  scan_bsum<<<GU, 256, 0, stream>>>(cursor_u, bsum, NU);
  scan_top<<<1, 256, 0, stream>>>(bsum, GU);
  scan_write<<<GU, 256, 0, stream>>>(cursor_u, bsum, rowptr_u, cursor_u, NU, NE);
  scatter_kernel<<<EB, 256, 0, stream>>>(arow, acol, avals, cursor_u, scol_u, sval_u, NE);

  hipMemsetAsync(cursor_i, 0, NI * sizeof(int), stream);
  hist_kernel<<<EB, 256, 0, stream>>>(acol, cursor_i, NE);
  scan_bsum<<<GI, 256, 0, stream>>>(cursor_i, bsum, NI);
  scan_top<<<1, 256, 0, stream>>>(bsum, GI);
  scan_write<<<GI, 256, 0, stream>>>(cursor_i, bsum, rowptr_i, cursor_i, NI, NE);
  scatter_kernel<<<EB, 256, 0, stream>>>(acol, arow, avals, cursor_i, scol_i, sval_i, NE);

  hipMemcpyAsync(cur_u, uE, (size_t)NU * DD * 4, hipMemcpyDeviceToDevice, stream);
  hipMemcpyAsync(cur_i, iE, (size_t)NI * DD * 4, hipMemcpyDeviceToDevice, stream);
  hipMemsetAsync(out + NB, 0, 2 * sizeof(float), stream);
  hipMemsetAsync(negb, 0, 4 * NB * sizeof(float), stream);
  hipMemsetAsync(sumg_u, 0, 2 * (size_t)NB * DD * 4, stream);  // sumg_u + sumg_i
  gaccum_both_kernel<<<dim3(NB, 2), 128, 0, stream>>>(uids, iids, uE, iE, sumg_u, sumg_i);

  // A(0) = E^T @ E for both sides
  atb0_kernel<<<512, 256, 0, stream>>>(uE, iE, Apart);
  reduce_both_kernel<<<32, 256, 0, stream>>>(Apart, A_u, A_i);

  for (int l = 0; l < 2; l++) {
    const float* Wt_l = Wt + (size_t)l * DD * DD;
    spmm_both_kernel<<<NU / 4 + NI / 4, 256, 0, stream>>>(
        rowptr_u, scol_u, sval_u, cur_i, gnn_u,
        rowptr_i, scol_i, sval_i, cur_u, gnn_i);
    chain_kernel<<<16, 256, 0, stream>>>(A_u, A_i, uhy, ihy,
        Wu + (size_t)l * 3 * HH * HH, Wi + (size_t)l * 3 * HH * HH, B_u, B_i);
    sslgath_both_kernel<<<dim3(NB / 32, 2), 128, 0, stream>>>(
        uids, iids, gnn_u, gnn_i, uE, iE, B_u, B_i, ggu, ghu, ggi, ghi);
    if (l == 0) {
      nmul_atb_kernel<1><<<512, 512, 0, stream>>>(uE, B_u, gnn_u, cur_u,
                                                  iE, B_i, gnn_i, cur_i, Apart);
      reduce_both_kernel<<<32, 256, 0, stream>>>(Apart, A_u, A_i);
    } else {
      nmul_atb_kernel<0><<<512, 512, 0, stream>>>(uE, B_u, gnn_u, cur_u,
                                                  iE, B_i, gnn_i, cur_i, nullptr);
    }
    gaccum_both_kernel<<<dim3(NB, 2), 128, 0, stream>>>(uids, iids, cur_u, cur_i,
                                                        sumg_u, sumg_i);
    normplain_kernel<<<256, 256, 0, stream>>>(ggu, ghu, ggi, ghi, Wt_l);
    gram_both_kernel<<<dim3(NB / 128, NB / 64, 2), 256, 0, stream>>>(
        ggu, ghu, ggi, ghi, negb + 2 * l * NB);
    sslfin_both_kernel<<<dim3(NB / 4, 2), 256, 0, stream>>>(
        ggu, ghu, ggi, ghi, negb + 2 * l * NB, out + NB);
  }

  preds_kernel<<<NB / 4, 256, 0, stream>>>(sumg_u, sumg_i, out);
  sumsq4_kernel<<<3200, 256, 0, stream>>>(uE, iE, uhy, ihy, out + NB + 1);
}